// Round 1
// baseline (560.446 us; speedup 1.0000x reference)
//
#include <hip/hip_runtime.h>
#include <hip/hip_bf16.h>

typedef __hip_bfloat16 bf16;
typedef __attribute__((ext_vector_type(8))) short short8;   // 8 bf16 (4 VGPRs)
typedef __attribute__((ext_vector_type(4))) short short4v;
typedef __attribute__((ext_vector_type(4))) float f32x4;

__device__ __forceinline__ short f2bf(float f) {            // f32 -> bf16 bits
    bf16 h = __float2bfloat16(f);
    return *reinterpret_cast<short*>(&h);
}
__device__ __forceinline__ float u2f(unsigned short u) {    // bf16 bits -> f32
    return __uint_as_float(((unsigned)u) << 16);
}

// Shapes: B=256, C=384, N=196 (14x14), N2=49 (7x7), HEADS=8, KD=16, D=64,
// NHKD=128, DH=512, OUT=384. Inputs fp32, output fp32.
// ws carve (149,258,240 B):
//   xT  bf16 [256][208][384]        @ 0
//   qin fp32 (aliased by attT bf16) @ 40,894,464
//   q_t bf16                        @ 60,162,048
//   kbf bf16 [256*8][208][32]       @ 66,584,576   (kd 16..31 = poison, finite)
//   vT  bf16 [256*8][64][208]       @ 93,847,552
//   wkv/pwb bf16 weights            @ 148,373,504 / 148,865,024

// ---------------------------------------------------------------------------
__global__ void k_cvt_w(const float* __restrict__ kw, const float* __restrict__ vw,
                        const float* __restrict__ pw, short* __restrict__ wkv,
                        short* __restrict__ pwb) {
    int idx = blockIdx.x * 256 + threadIdx.x;
    if (idx < 245760) {
        wkv[idx] = f2bf(idx < 49152 ? kw[idx] : vw[idx - 49152]);
    } else if (idx < 442368) {
        int j = idx - 245760;
        pwb[j] = f2bf(pw[j]);
    }
}

// ---------------------------------------------------------------------------
// xT[b][n][c] = bf16(x[b][c][n]); rows n=196..207 zeroed. LDS tile transpose.
__global__ __launch_bounds__(256) void k_cvt_x(const float* __restrict__ x,
                                               short* __restrict__ xT) {
    __shared__ short sT[64 * 198];
    int ct = blockIdx.x, b = blockIdx.y, tid = threadIdx.x;
    for (int i = tid; i < 64 * 196; i += 256) {
        int c = i / 196, n = i % 196;
        sT[c * 198 + n] = f2bf(x[((long)b * 384 + ct * 64 + c) * 196 + n]);
    }
    __syncthreads();
    for (int i = tid; i < 196 * 64; i += 256) {
        int n = i / 64, c = i % 64;
        xT[((long)b * 208 + n) * 384 + ct * 64 + c] = sT[c * 198 + n];
    }
    for (int i = tid; i < 12 * 64; i += 256) {
        int n = 196 + i / 64, c = i % 64;
        xT[((long)b * 208 + n) * 384 + ct * 64 + c] = 0;
    }
}

// ---------------------------------------------------------------------------
__global__ void k_qin(const float* __restrict__ x, const float* __restrict__ w,
                      const float* __restrict__ bias, float* __restrict__ qin) {
    int idx = blockIdx.x * 256 + threadIdx.x;
    if (idx >= 256 * 384 * 49) return;
    int p = idx % 49; int t = idx / 49; int c = t % 384; int b = t / 384;
    int h2 = p / 7, w2 = p % 7;
    const float* xb = x + ((long)b * 384 + c) * 196;
    const float* wc = w + c * 9;
    float acc = bias[c];
#pragma unroll
    for (int kh = 0; kh < 3; kh++) {
        int hin = 2 * h2 - 1 + kh;
        if (hin < 0 || hin >= 14) continue;
#pragma unroll
        for (int kw = 0; kw < 3; kw++) {
            int win = 2 * w2 - 1 + kw;
            if (win < 0 || win >= 14) continue;
            acc += xb[hin * 14 + win] * wc[kh * 3 + kw];
        }
    }
    acc += xb[(2 * h2) * 14 + 2 * w2];
    qin[idx] = acc;
}

// ---------------------------------------------------------------------------
// q_t now emitted as bf16 (k_attn converted to bf16 anyway -> numerics equal).
__global__ void k_qproj(const float* __restrict__ qin, const float* __restrict__ w,
                        const float* __restrict__ bias, const float* __restrict__ bns,
                        const float* __restrict__ bnb, short* __restrict__ q_t) {
    int idx = blockIdx.x * 256 + threadIdx.x;
    int p = idx % 49; int t = idx / 49; int ocg = t % 16; int b = t / 16;
    if (b >= 256) return;
    int oc0 = ocg * 8;
    float acc[8] = {0.f,0.f,0.f,0.f,0.f,0.f,0.f,0.f};
    const float* xb = qin + (long)b * 384 * 49 + p;
    const float* wb = w + oc0 * 384;
    for (int c = 0; c < 384; c++) {
        float xv = xb[c * 49];
#pragma unroll
        for (int j = 0; j < 8; j++) acc[j] += xv * wb[j * 384 + c];
    }
#pragma unroll
    for (int j = 0; j < 8; j++) {
        int oc = oc0 + j;
        float val = bns[oc] * (acc[j] + bias[oc]) + bnb[oc];
        int h = oc >> 4, kd = oc & 15;
        q_t[(((long)b * 8 + h) * 49 + p) * 16 + kd] = f2bf(val);
    }
}

// ---------------------------------------------------------------------------
// K+V 1x1 conv via MFMA (operand-swapped, BK=32, reg-prefetch). Emits bf16:
// kbf[(bh*208+n)*32+kd] and vT[(bh*64+d)*208+n].
__global__ __launch_bounds__(256) void k_kv_mfma(const short* __restrict__ wkv,
        const short* __restrict__ xT,
        const float* __restrict__ kb, const float* __restrict__ kbs,
        const float* __restrict__ kbb, const float* __restrict__ vb,
        const float* __restrict__ vbs, const float* __restrict__ vbb,
        short* __restrict__ kbf, short* __restrict__ vT) {
    __shared__ short sA[128 * 40];       // w: [oc][k32]
    __shared__ short sB[208 * 40];       // x: [n][k32]
    int b = blockIdx.y, ocblk = blockIdx.x, tid = threadIdx.x;
    int wave = tid >> 6, lane = tid & 63, quad = lane >> 4, l15 = lane & 15;
    int ocbase = ocblk * 128;

    f32x4 acc[2][13];
#pragma unroll
    for (int t = 0; t < 2; t++)
#pragma unroll
        for (int nt = 0; nt < 13; nt++) acc[t][nt] = (f32x4){0.f,0.f,0.f,0.f};

    short8 pA[2], pB[4], nA[2], nB[4];
    {
#pragma unroll
        for (int j = 0; j < 2; j++) {
            int s = tid + j * 256, r = s >> 2, c = s & 3;
            pA[j] = *(const short8*)(wkv + (long)(ocbase + r) * 384 + c * 8);
        }
#pragma unroll
        for (int j = 0; j < 4; j++) {
            int s = tid + j * 256;
            if (s < 832) {
                int r = s >> 2, c = s & 3;
                pB[j] = *(const short8*)(xT + ((long)b * 208 + r) * 384 + c * 8);
            }
        }
    }

    for (int ct = 0; ct < 12; ct++) {
#pragma unroll
        for (int j = 0; j < 2; j++) {
            int s = tid + j * 256, r = s >> 2, c = s & 3;
            *(short8*)(sA + r * 40 + c * 8) = pA[j];
        }
#pragma unroll
        for (int j = 0; j < 4; j++) {
            int s = tid + j * 256;
            if (s < 832) {
                int r = s >> 2, c = s & 3;
                *(short8*)(sB + r * 40 + c * 8) = pB[j];
            }
        }
        __syncthreads();
        if (ct < 11) {
            int cn = ct + 1;
#pragma unroll
            for (int j = 0; j < 2; j++) {
                int s = tid + j * 256, r = s >> 2, c = s & 3;
                nA[j] = *(const short8*)(wkv + (long)(ocbase + r) * 384 + cn * 32 + c * 8);
            }
#pragma unroll
            for (int j = 0; j < 4; j++) {
                int s = tid + j * 256;
                if (s < 832) {
                    int r = s >> 2, c = s & 3;
                    nB[j] = *(const short8*)(xT + ((long)b * 208 + r) * 384 + cn * 32 + c * 8);
                }
            }
        }
        short8 bw0 = *(const short8*)(sA + (wave * 32 + l15) * 40 + quad * 8);
        short8 bw1 = *(const short8*)(sA + (wave * 32 + 16 + l15) * 40 + quad * 8);
#pragma unroll
        for (int nt = 0; nt < 13; nt++) {
            short8 ax = *(const short8*)(sB + (nt * 16 + l15) * 40 + quad * 8);
            acc[0][nt] = __builtin_amdgcn_mfma_f32_16x16x32_bf16(ax, bw0, acc[0][nt], 0, 0, 0);
            acc[1][nt] = __builtin_amdgcn_mfma_f32_16x16x32_bf16(ax, bw1, acc[1][nt], 0, 0, 0);
        }
        __syncthreads();
#pragma unroll
        for (int j = 0; j < 2; j++) pA[j] = nA[j];
#pragma unroll
        for (int j = 0; j < 4; j++) pB[j] = nB[j];
    }

    // epilogue: row (quad*4+r) = n (ALL n 0..207 stored, pads finite), col = oc
#pragma unroll
    for (int t = 0; t < 2; t++) {
        int oc = ocbase + wave * 32 + t * 16 + l15;
        if (ocblk == 0) {                             // K outputs (oc < 128)
            int hh = oc >> 4, kd = oc & 15;
            float sc = kbs[oc], bi = kb[oc], bb2 = kbb[oc];
            short* kbase = kbf + ((long)(b * 8 + hh) * 208) * 32 + kd;
#pragma unroll
            for (int nt = 0; nt < 13; nt++) {
                int n0 = nt * 16 + quad * 4;
#pragma unroll
                for (int r = 0; r < 4; r++)
                    kbase[(long)(n0 + r) * 32] = f2bf(sc * (acc[t][nt][r] + bi) + bb2);
            }
        } else {                                      // V outputs
            int cc = oc - 128, hh = cc >> 6, d = cc & 63;
            float sc = vbs[cc], bi = vb[cc], bb2 = vbb[cc];
            short* vbase = vT + ((long)(b * 8 + hh) * 64 + d) * 208;
#pragma unroll
            for (int nt = 0; nt < 13; nt++) {
                int n0 = nt * 16 + quad * 4;
                short4v ov;
                ov.x = f2bf(sc * (acc[t][nt][0] + bi) + bb2);
                ov.y = f2bf(sc * (acc[t][nt][1] + bi) + bb2);
                ov.z = f2bf(sc * (acc[t][nt][2] + bi) + bb2);
                ov.w = f2bf(sc * (acc[t][nt][3] + bi) + bb2);
                *(short4v*)(vbase + n0) = ov;
            }
        }
    }
}

// ---------------------------------------------------------------------------
// attention per (b,h), fully MFMA. LDS cut 56KB -> 29KB (occupancy 2 -> 4-5
// blocks/CU): V is NOT staged (private per block, L2-resident -> read direct
// from global in both PV MFMA and the v_local 9-tap epilogue). Strides padded
// (sQ/sK 40, sP 232) to break bank-stride-16 conflicts. No barrier between
// P-write and PV (each wave consumes only its own 16 P rows).
__global__ __launch_bounds__(256, 4) void k_attn(const short* __restrict__ q_t,
        const short* __restrict__ kbf, const short* __restrict__ vT,
        const float* __restrict__ bias_tab,
        const float* __restrict__ vlw, const float* __restrict__ vlb,
        const float* __restrict__ vlbs, const float* __restrict__ vlbb,
        short* __restrict__ attT) {
    __shared__ short smem[14848];            // 29,696 B
    short* sQ = smem;                        // [64][40] (cols 0..31 live)
    short* sK = smem + 2560;                 // [208][40]
    short* sP = smem;                        // [64][232] (aliases phase A)
    int bh = blockIdx.x, b = bh >> 3, h = bh & 7, tid = threadIdx.x;
    int wave = tid >> 6, lane = tid & 63, quad = lane >> 4, l15 = lane & 15;

    // stage Q (bf16 copy, zero pads kd 16..31 / rows 49..63) and K
    const short8* qg8 = (const short8*)(q_t + (long)bh * 784);
    for (int i = tid; i < 320; i += 256) {   // 64 rows x 5 short8
        int p = i / 5, c8 = i % 5;
        short8 v = {0,0,0,0,0,0,0,0};
        if (p < 49 && c8 < 2) v = qg8[p * 2 + c8];
        *(short8*)(sQ + p * 40 + c8 * 8) = v;
    }
    const short* kg = kbf + (long)bh * 6656;
    for (int i = tid; i < 832; i += 256) {
        int r = i >> 2, c = i & 3;
        *(short8*)(sK + r * 40 + c * 8) = *(const short8*)(kg + i * 8);
    }
    __syncthreads();

    // QK^T: wave owns p-tile [wave*16, +16)
    f32x4 s[13];
    short8 aQ = *(const short8*)(sQ + (wave * 16 + l15) * 40 + quad * 8);
#pragma unroll
    for (int nt = 0; nt < 13; nt++) {
        short8 bK = *(const short8*)(sK + (nt * 16 + l15) * 40 + quad * 8);
        s[nt] = __builtin_amdgcn_mfma_f32_16x16x32_bf16(aQ, bK, (f32x4){0,0,0,0}, 0, 0, 0);
    }
    __syncthreads();        // all waves done with sQ/sK; region becomes sP

    // scale + bias + n-mask  (D map: p = wave*16+quad*4+r, n = nt*16+l15)
#pragma unroll
    for (int nt = 0; nt < 13; nt++) {
        int n = nt * 16 + l15;
#pragma unroll
        for (int r = 0; r < 4; r++) {
            int p = wave * 16 + quad * 4 + r;
            float v = s[nt][r] * 0.25f;
            if (n < 196) {
                if (p < 49) v += bias_tab[((long)h * 49 + p) * 196 + n];
            } else v = -1e30f;
            s[nt][r] = v;
        }
    }
    // register softmax across n (13 regs x 16 lanes per row)
#pragma unroll
    for (int r = 0; r < 4; r++) {
        float m = -1e30f;
#pragma unroll
        for (int nt = 0; nt < 13; nt++) m = fmaxf(m, s[nt][r]);
        m = fmaxf(m, __shfl_xor(m, 1)); m = fmaxf(m, __shfl_xor(m, 2));
        m = fmaxf(m, __shfl_xor(m, 4)); m = fmaxf(m, __shfl_xor(m, 8));
        float sum = 0.f;
#pragma unroll
        for (int nt = 0; nt < 13; nt++) {
            float e = __expf(s[nt][r] - m);
            s[nt][r] = e; sum += e;
        }
        sum += __shfl_xor(sum, 1); sum += __shfl_xor(sum, 2);
        sum += __shfl_xor(sum, 4); sum += __shfl_xor(sum, 8);
        float inv = 1.f / sum;
#pragma unroll
        for (int nt = 0; nt < 13; nt++) s[nt][r] *= inv;
    }
    // write P (bf16); nt=13 zeroes pad cols 208..223 of this wave's own rows
#pragma unroll
    for (int nt = 0; nt < 14; nt++) {
        int n = nt * 16 + l15;
#pragma unroll
        for (int r = 0; r < 4; r++) {
            short val = 0;
            if (nt < 13) val = f2bf(s[nt][r]);
            sP[(wave * 16 + quad * 4 + r) * 232 + n] = val;
        }
    }
    // NO barrier: PV reads only this wave's own 16 rows of sP.

    // PV: O[p][d], K = 224 (7 steps of 32); V fragments straight from global
    // (26.6KB per block, L2-resident; pad cols 208..223 read garbage bf16 but
    // multiply P=0).
    const short* vg = vT + (long)bh * 13312;
    f32x4 o[4];
#pragma unroll
    for (int dt = 0; dt < 4; dt++) o[dt] = (f32x4){0.f,0.f,0.f,0.f};
#pragma unroll
    for (int ks = 0; ks < 7; ks++) {
        short8 aP = *(const short8*)(sP + (wave * 16 + l15) * 232 + ks * 32 + quad * 8);
#pragma unroll
        for (int dt = 0; dt < 4; dt++) {
            short8 bV = *(const short8*)(vg + (dt * 16 + l15) * 208 + ks * 32 + quad * 8);
            o[dt] = __builtin_amdgcn_mfma_f32_16x16x32_bf16(aP, bV, o[dt], 0, 0, 0);
        }
    }

    // epilogue: v_local 9-tap from global V + BN + ReLU -> attT
#pragma unroll
    for (int r = 0; r < 4; r++) {
        int p = wave * 16 + quad * 4 + r;
        if (p >= 49) continue;
        int h2 = p / 7, w2 = p % 7;
#pragma unroll
        for (int dt = 0; dt < 4; dt++) {
            int d = dt * 16 + l15, c = h * 64 + d;
            float acc2 = vlb[c];
            const float* wc = vlw + c * 9;
            const short* vrow = vg + d * 208;
#pragma unroll
            for (int kh = 0; kh < 3; kh++) {
                int hin = 2 * h2 - 1 + kh;
                if (hin < 0 || hin >= 14) continue;
#pragma unroll
                for (int kw = 0; kw < 3; kw++) {
                    int win = 2 * w2 - 1 + kw;
                    if (win < 0 || win >= 14) continue;
                    acc2 += u2f((unsigned short)vrow[hin * 14 + win]) * wc[kh * 3 + kw];
                }
            }
            float vl = vlbs[c] * acc2 + vlbb[c];
            attT[((long)b * 64 + p) * 512 + h * 64 + d]
                = f2bf(fmaxf(o[dt][r] + vl, 0.f));
        }
    }
    for (int i = tid; i < 960; i += 256) {   // zero attT rows p 49..63
        int p = 49 + i / 64, d = i % 64;
        attT[((long)b * 64 + p) * 512 + h * 64 + d] = 0;
    }
}

// ---------------------------------------------------------------------------
// out = bn(conv1x1(relu(att))) via MFMA.
__global__ __launch_bounds__(256) void k_pconv_mfma(const short* __restrict__ attT,
        const short* __restrict__ pwb, const float* __restrict__ bias,
        const float* __restrict__ bns, const float* __restrict__ bnb,
        float* __restrict__ out) {
    __shared__ short sA[128 * 72];
    __shared__ short sB[64 * 72];
    int b = blockIdx.y, ocblk = blockIdx.x, tid = threadIdx.x;
    int wave = tid >> 6, lane = tid & 63, quad = lane >> 4, l15 = lane & 15;
    int ocbase = ocblk * 128;

    f32x4 acc[2][4];
#pragma unroll
    for (int t = 0; t < 2; t++)
#pragma unroll
        for (int nt = 0; nt < 4; nt++) acc[t][nt] = (f32x4){0.f,0.f,0.f,0.f};

    for (int ct = 0; ct < 8; ct++) {
        for (int i = tid; i < 1024; i += 256) {
            int r = i >> 3, c8 = i & 7;
            *(short8*)(sA + r * 72 + c8 * 8)
                = *(const short8*)(pwb + (long)(ocbase + r) * 512 + ct * 64 + c8 * 8);
        }
        for (int i = tid; i < 512; i += 256) {
            int r = i >> 3, c8 = i & 7;
            *(short8*)(sB + r * 72 + c8 * 8)
                = *(const short8*)(attT + ((long)b * 64 + r) * 512 + ct * 64 + c8 * 8);
        }
        __syncthreads();
        short8 a00 = *(const short8*)(sA + (wave * 32 + l15) * 72 + quad * 8);
        short8 a01 = *(const short8*)(sA + (wave * 32 + l15) * 72 + 32 + quad * 8);
        short8 a10 = *(const short8*)(sA + (wave * 32 + 16 + l15) * 72 + quad * 8);
        short8 a11 = *(const short8*)(sA + (wave * 32 + 16 + l15) * 72 + 32 + quad * 8);
#pragma unroll
        for (int nt = 0; nt < 4; nt++) {
            short8 b0 = *(const short8*)(sB + (nt * 16 + l15) * 72 + quad * 8);
            short8 b1 = *(const short8*)(sB + (nt * 16 + l15) * 72 + 32 + quad * 8);
            acc[0][nt] = __builtin_amdgcn_mfma_f32_16x16x32_bf16(a00, b0, acc[0][nt], 0, 0, 0);
            acc[0][nt] = __builtin_amdgcn_mfma_f32_16x16x32_bf16(a01, b1, acc[0][nt], 0, 0, 0);
            acc[1][nt] = __builtin_amdgcn_mfma_f32_16x16x32_bf16(a10, b0, acc[1][nt], 0, 0, 0);
            acc[1][nt] = __builtin_amdgcn_mfma_f32_16x16x32_bf16(a11, b1, acc[1][nt], 0, 0, 0);
        }
        __syncthreads();
    }

#pragma unroll
    for (int t = 0; t < 2; t++) {
#pragma unroll
        for (int nt = 0; nt < 4; nt++) {
            int p = nt * 16 + l15;
            if (p >= 49) continue;
#pragma unroll
            for (int r = 0; r < 4; r++) {
                int oc = ocbase + wave * 32 + t * 16 + quad * 4 + r;
                out[((long)b * 384 + oc) * 49 + p]
                    = bns[oc] * (acc[t][nt][r] + bias[oc]) + bnb[oc];
            }
        }
    }
}

// ---------------------------------------------------------------------------
extern "C" void kernel_launch(void* const* d_in, const int* in_sizes, int n_in,
                              void* d_out, int out_size, void* d_ws, size_t ws_size,
                              hipStream_t stream) {
    const float* x    = (const float*)d_in[0];
    const float* qlw  = (const float*)d_in[1];
    const float* qlb  = (const float*)d_in[2];
    const float* qpw  = (const float*)d_in[3];
    const float* qpb  = (const float*)d_in[4];
    const float* qbs  = (const float*)d_in[5];
    const float* qbb  = (const float*)d_in[6];
    const float* kw   = (const float*)d_in[7];
    const float* kb   = (const float*)d_in[8];
    const float* kbs  = (const float*)d_in[9];
    const float* kbb  = (const float*)d_in[10];
    const float* vw   = (const float*)d_in[11];
    const float* vb   = (const float*)d_in[12];
    const float* vbs  = (const float*)d_in[13];
    const float* vbb  = (const float*)d_in[14];
    const float* vlw  = (const float*)d_in[15];
    const float* vlb  = (const float*)d_in[16];
    const float* vlbs = (const float*)d_in[17];
    const float* vlbb = (const float*)d_in[18];
    const float* btab = (const float*)d_in[19];
    const float* pw   = (const float*)d_in[20];
    const float* pb   = (const float*)d_in[21];
    const float* pbs  = (const float*)d_in[22];
    const float* pbb  = (const float*)d_in[23];
    float* out = (float*)d_out;

    char* W = (char*)d_ws;
    short* xT   = (short*)(W + 0);
    float* qin  = (float*)(W + 40894464);     // aliased by attT after qproj
    short* attT = (short*)(W + 40894464);
    short* q_t  = (short*)(W + 60162048);     // bf16 now
    short* kbf  = (short*)(W + 66584576);
    short* vT   = (short*)(W + 93847552);
    short* wkv  = (short*)(W + 148373504);
    short* pwb  = (short*)(W + 148865024);    // end 149,258,240
    if (ws_size < 149258240) return;

    k_cvt_w     <<< 1728, 256, 0, stream>>>(kw, vw, pw, wkv, pwb);
    k_cvt_x     <<<dim3(6, 256), 256, 0, stream>>>(x, xT);
    k_qin       <<<18816, 256, 0, stream>>>(x, qlw, qlb, qin);
    k_qproj     <<<  784, 256, 0, stream>>>(qin, qpw, qpb, qbs, qbb, q_t);
    k_kv_mfma   <<<dim3(5, 256), 256, 0, stream>>>(wkv, xT, kb, kbs, kbb,
                                                   vb, vbs, vbb, kbf, vT);
    k_attn      <<< 2048, 256, 0, stream>>>(q_t, kbf, vT, btab,
                                            vlw, vlb, vlbs, vlbb, attT);
    k_pconv_mfma<<<dim3(3, 256), 256, 0, stream>>>(attT, pwb, pb, pbs, pbb, out);
}

// Round 2
// 508.274 us; speedup vs baseline: 1.1026x; 1.1026x over previous
//
#include <hip/hip_runtime.h>
#include <hip/hip_bf16.h>

typedef __hip_bfloat16 bf16;
typedef __attribute__((ext_vector_type(8))) short short8;   // 8 bf16 (4 VGPRs)
typedef __attribute__((ext_vector_type(4))) short short4v;
typedef __attribute__((ext_vector_type(4))) float f32x4;

__device__ __forceinline__ short f2bf(float f) {            // f32 -> bf16 bits
    bf16 h = __float2bfloat16(f);
    return *reinterpret_cast<short*>(&h);
}
__device__ __forceinline__ float u2f(unsigned short u) {    // bf16 bits -> f32
    return __uint_as_float(((unsigned)u) << 16);
}

// Shapes: B=256, C=384, N=196 (14x14), N2=49 (7x7), HEADS=8, KD=16, D=64,
// NHKD=128, DH=512, OUT=384. Inputs fp32, output fp32.
// ws carve (143,654,912 B):
//   xT   bf16 [256][208][384]            @ 0
//   qinT bf16 [256][64][384] (alias attT)@ 40,894,464
//   attT bf16 [256][64][512]             @ 40,894,464
//   q_t  bf16 [256*8][49][16]            @ 57,671,680
//   kbf  bf16 [256*8][208][32]           @ 60,882,944  (kd 16..31 finite junk)
//   vT   bf16 [256*8][64][208]           @ 88,145,920
//   wkv  bf16 [768][384] (k,v,qproj w)   @ 142,671,872
//   pwb  bf16 [384][512]                 @ 143,261,696

// ---------------------------------------------------------------------------
// k_prep: fused {x transpose+cvt (blocks 0..1535)} {weight cvt (1536..3455)}
//         {q_local 3x3 dw conv + pool -> qinT bf16 (3456..19839)}
__global__ __launch_bounds__(256) void k_prep(const float* __restrict__ x,
        const float* __restrict__ qlw, const float* __restrict__ qlb,
        const float* __restrict__ kw, const float* __restrict__ vw,
        const float* __restrict__ qpw, const float* __restrict__ pw,
        short* __restrict__ xT, short* __restrict__ qinT,
        short* __restrict__ wkv, short* __restrict__ pwb) {
    __shared__ short sT[64 * 198];
    int bid = blockIdx.x, tid = threadIdx.x;
    if (bid < 1536) {
        // ---- xT[b][n][c] = bf16(x[b][c][n]); rows 196..207 zeroed
        int ct = bid % 6, b = bid / 6;
        for (int i = tid; i < 64 * 196; i += 256) {
            int c = i / 196, n = i % 196;
            sT[c * 198 + n] = f2bf(x[((long)b * 384 + ct * 64 + c) * 196 + n]);
        }
        __syncthreads();
        for (int i = tid; i < 196 * 64; i += 256) {
            int n = i / 64, c = i % 64;
            xT[((long)b * 208 + n) * 384 + ct * 64 + c] = sT[c * 198 + n];
        }
        for (int i = tid; i < 12 * 64; i += 256) {
            int n = 196 + i / 64, c = i % 64;
            xT[((long)b * 208 + n) * 384 + ct * 64 + c] = 0;
        }
    } else if (bid < 3456) {
        // ---- weights -> bf16: wkv = [kw | vw | qpw], pwb = pw
        int idx = (bid - 1536) * 256 + tid;
        if (idx < 294912) {
            float v;
            if (idx < 49152) v = kw[idx];
            else if (idx < 245760) v = vw[idx - 49152];
            else v = qpw[idx - 245760];
            wkv[idx] = f2bf(v);
        } else {
            int j = idx - 294912;
            pwb[j] = f2bf(pw[j]);
        }
    } else {
        // ---- qinT[b][p][c] = bf16(dwconv3x3s2(x)+b+pool); rows p>=49 zero
        int qb = bid - 3456;
        int b = qb >> 6, p = qb & 63;
        if (p >= 49) {
            for (int c = tid; c < 384; c += 256)
                qinT[((long)b * 64 + p) * 384 + c] = 0;
            return;
        }
        int h2 = p / 7, w2 = p % 7;
        for (int c = tid; c < 384; c += 256) {
            const float* xb = x + ((long)b * 384 + c) * 196;
            const float* wc = qlw + c * 9;
            float acc = qlb[c];
#pragma unroll
            for (int kh = 0; kh < 3; kh++) {
                int hin = 2 * h2 - 1 + kh;
                if (hin < 0 || hin >= 14) continue;
#pragma unroll
                for (int kk = 0; kk < 3; kk++) {
                    int win = 2 * w2 - 1 + kk;
                    if (win < 0 || win >= 14) continue;
                    acc += xb[hin * 14 + win] * wc[kh * 3 + kk];
                }
            }
            acc += xb[(2 * h2) * 14 + 2 * w2];
            qinT[((long)b * 64 + p) * 384 + c] = f2bf(acc);
        }
    }
}

// ---------------------------------------------------------------------------
// K+V+Q 1x1 convs via MFMA. ocblk 0: K, 1..4: V, 5: Q (B = qinT, 64 rows).
__global__ __launch_bounds__(256) void k_kv_mfma(const short* __restrict__ wkv,
        const short* __restrict__ xT, const short* __restrict__ qinT,
        const float* __restrict__ kb, const float* __restrict__ kbs,
        const float* __restrict__ kbb, const float* __restrict__ vb,
        const float* __restrict__ vbs, const float* __restrict__ vbb,
        const float* __restrict__ qpb, const float* __restrict__ qbs,
        const float* __restrict__ qbb,
        short* __restrict__ kbf, short* __restrict__ vT, short* __restrict__ q_t) {
    __shared__ short sA[128 * 40];       // w: [oc][k32]
    __shared__ short sB[208 * 40];       // x: [n][k32]
    int b = blockIdx.y, ocblk = blockIdx.x, tid = threadIdx.x;
    int wave = tid >> 6, lane = tid & 63, quad = lane >> 4, l15 = lane & 15;

    if (ocblk == 5) {
        // ---------------- Q projection: [128 oc] x [64 p] over K=384
        f32x4 qa[2][4];
#pragma unroll
        for (int t = 0; t < 2; t++)
#pragma unroll
            for (int nt = 0; nt < 4; nt++) qa[t][nt] = (f32x4){0.f,0.f,0.f,0.f};
        for (int ct = 0; ct < 12; ct++) {
#pragma unroll
            for (int j = 0; j < 2; j++) {
                int s = tid + j * 256, r = s >> 2, c = s & 3;
                *(short8*)(sA + r * 40 + c * 8)
                    = *(const short8*)(wkv + (long)(640 + r) * 384 + ct * 32 + c * 8);
            }
            {
                int r = tid >> 2, c = tid & 3;
                *(short8*)(sB + r * 40 + c * 8)
                    = *(const short8*)(qinT + ((long)b * 64 + r) * 384 + ct * 32 + c * 8);
            }
            __syncthreads();
            short8 bw0 = *(const short8*)(sA + (wave * 32 + l15) * 40 + quad * 8);
            short8 bw1 = *(const short8*)(sA + (wave * 32 + 16 + l15) * 40 + quad * 8);
#pragma unroll
            for (int nt = 0; nt < 4; nt++) {
                short8 ax = *(const short8*)(sB + (nt * 16 + l15) * 40 + quad * 8);
                qa[0][nt] = __builtin_amdgcn_mfma_f32_16x16x32_bf16(ax, bw0, qa[0][nt], 0, 0, 0);
                qa[1][nt] = __builtin_amdgcn_mfma_f32_16x16x32_bf16(ax, bw1, qa[1][nt], 0, 0, 0);
            }
            __syncthreads();
        }
#pragma unroll
        for (int t = 0; t < 2; t++) {
            int oc = wave * 32 + t * 16 + l15;          // 0..127
            int hh = oc >> 4, kd = oc & 15;
            float sc = qbs[oc], bi = qpb[oc], bb2 = qbb[oc];
#pragma unroll
            for (int nt = 0; nt < 4; nt++) {
#pragma unroll
                for (int r = 0; r < 4; r++) {
                    int p = nt * 16 + quad * 4 + r;
                    if (p < 49)
                        q_t[(((long)b * 8 + hh) * 49 + p) * 16 + kd]
                            = f2bf(sc * (qa[t][nt][r] + bi) + bb2);
                }
            }
        }
        return;
    }

    // ---------------- K/V path (unchanged structure, reg-prefetch, BK=32)
    int ocbase = ocblk * 128;
    f32x4 acc[2][13];
#pragma unroll
    for (int t = 0; t < 2; t++)
#pragma unroll
        for (int nt = 0; nt < 13; nt++) acc[t][nt] = (f32x4){0.f,0.f,0.f,0.f};

    short8 pA[2], pB[4], nA[2], nB[4];
    {
#pragma unroll
        for (int j = 0; j < 2; j++) {
            int s = tid + j * 256, r = s >> 2, c = s & 3;
            pA[j] = *(const short8*)(wkv + (long)(ocbase + r) * 384 + c * 8);
        }
#pragma unroll
        for (int j = 0; j < 4; j++) {
            int s = tid + j * 256;
            if (s < 832) {
                int r = s >> 2, c = s & 3;
                pB[j] = *(const short8*)(xT + ((long)b * 208 + r) * 384 + c * 8);
            }
        }
    }

    for (int ct = 0; ct < 12; ct++) {
#pragma unroll
        for (int j = 0; j < 2; j++) {
            int s = tid + j * 256, r = s >> 2, c = s & 3;
            *(short8*)(sA + r * 40 + c * 8) = pA[j];
        }
#pragma unroll
        for (int j = 0; j < 4; j++) {
            int s = tid + j * 256;
            if (s < 832) {
                int r = s >> 2, c = s & 3;
                *(short8*)(sB + r * 40 + c * 8) = pB[j];
            }
        }
        __syncthreads();
        if (ct < 11) {
            int cn = ct + 1;
#pragma unroll
            for (int j = 0; j < 2; j++) {
                int s = tid + j * 256, r = s >> 2, c = s & 3;
                nA[j] = *(const short8*)(wkv + (long)(ocbase + r) * 384 + cn * 32 + c * 8);
            }
#pragma unroll
            for (int j = 0; j < 4; j++) {
                int s = tid + j * 256;
                if (s < 832) {
                    int r = s >> 2, c = s & 3;
                    nB[j] = *(const short8*)(xT + ((long)b * 208 + r) * 384 + cn * 32 + c * 8);
                }
            }
        }
        short8 bw0 = *(const short8*)(sA + (wave * 32 + l15) * 40 + quad * 8);
        short8 bw1 = *(const short8*)(sA + (wave * 32 + 16 + l15) * 40 + quad * 8);
#pragma unroll
        for (int nt = 0; nt < 13; nt++) {
            short8 ax = *(const short8*)(sB + (nt * 16 + l15) * 40 + quad * 8);
            acc[0][nt] = __builtin_amdgcn_mfma_f32_16x16x32_bf16(ax, bw0, acc[0][nt], 0, 0, 0);
            acc[1][nt] = __builtin_amdgcn_mfma_f32_16x16x32_bf16(ax, bw1, acc[1][nt], 0, 0, 0);
        }
        __syncthreads();
#pragma unroll
        for (int j = 0; j < 2; j++) pA[j] = nA[j];
#pragma unroll
        for (int j = 0; j < 4; j++) pB[j] = nB[j];
    }

    // epilogue: row (quad*4+r) = n (ALL n 0..207 stored, pads finite), col = oc
#pragma unroll
    for (int t = 0; t < 2; t++) {
        int oc = ocbase + wave * 32 + t * 16 + l15;
        if (ocblk == 0) {                             // K outputs (oc < 128)
            int hh = oc >> 4, kd = oc & 15;
            float sc = kbs[oc], bi = kb[oc], bb2 = kbb[oc];
            short* kbase = kbf + ((long)(b * 8 + hh) * 208) * 32 + kd;
#pragma unroll
            for (int nt = 0; nt < 13; nt++) {
                int n0 = nt * 16 + quad * 4;
#pragma unroll
                for (int r = 0; r < 4; r++)
                    kbase[(long)(n0 + r) * 32] = f2bf(sc * (acc[t][nt][r] + bi) + bb2);
            }
        } else {                                      // V outputs
            int cc = oc - 128, hh = cc >> 6, d = cc & 63;
            float sc = vbs[cc], bi = vb[cc], bb2 = vbb[cc];
            short* vbase = vT + ((long)(b * 8 + hh) * 64 + d) * 208;
#pragma unroll
            for (int nt = 0; nt < 13; nt++) {
                int n0 = nt * 16 + quad * 4;
                short4v ov;
                ov.x = f2bf(sc * (acc[t][nt][0] + bi) + bb2);
                ov.y = f2bf(sc * (acc[t][nt][1] + bi) + bb2);
                ov.z = f2bf(sc * (acc[t][nt][2] + bi) + bb2);
                ov.w = f2bf(sc * (acc[t][nt][3] + bi) + bb2);
                *(short4v*)(vbase + n0) = ov;
            }
        }
    }
}

// ---------------------------------------------------------------------------
// attention per (b,h), swapped-operand QK^T: s2 = mfma(K,Q) puts a full
// softmax row in each lane (in-lane reduce + 2 shuffles). bias_tab loaded as
// 13 f32x4 at kernel start; V loads issued under softmax, staged to LDS
// (stride 232). P transposed for PV via a 5KB wave-private per-ks LDS tile
// (DS per-wave FIFO => no barrier). 34.8KB LDS -> 4 blocks/CU.
__global__ __launch_bounds__(256, 3) void k_attn(const short* __restrict__ q_t,
        const short* __restrict__ kbf, const short* __restrict__ vT,
        const float* __restrict__ bias_tab,
        const float* __restrict__ vlw, const float* __restrict__ vlb,
        const float* __restrict__ vlbs, const float* __restrict__ vlbb,
        short* __restrict__ attT) {
    __shared__ short smem[17408];            // 34,816 B
    short* sQ = smem;                        // [64][40] phase A
    short* sK = smem + 2560;                 // [208][40] phase A
    short* sV = smem;                        // [64][232] phase B (alias A)
    short* sP = smem + 14848;                // [64][40] per-ks P tile
    int bh = blockIdx.x, b = bh >> 3, h = bh & 7, tid = threadIdx.x;
    int wave = tid >> 6, lane = tid & 63, quad = lane >> 4, l15 = lane & 15;
    int prow = wave * 16 + l15;

    // ---- issue Q, K, bias loads (all independent)
    const short8* qg8 = (const short8*)(q_t + (long)bh * 784);
    short8 qv[2]; int qp[2], qc[2];
#pragma unroll
    for (int j = 0; j < 2; j++) {
        int i = tid + j * 256;
        qp[j] = i / 5; qc[j] = i % 5;
        qv[j] = (short8){0,0,0,0,0,0,0,0};
        if (i < 320 && qp[j] < 49 && qc[j] < 2) qv[j] = qg8[qp[j] * 2 + qc[j]];
    }
    const short8* kg8 = (const short8*)(kbf + (long)bh * 6656);
    short8 kv[4];
#pragma unroll
    for (int j = 0; j < 4; j++) {
        int i = tid + j * 256;
        if (i < 832) kv[j] = kg8[i];
    }
    int pb = prow < 49 ? prow : 48;
    const float* bp = bias_tab + ((long)(h * 49 + pb) * 196 + quad * 4);
    f32x4 bi[13];
#pragma unroll
    for (int nt = 0; nt < 13; nt++) bi[nt] = *(const f32x4*)(bp + nt * 16);

    // ---- stage Q, K
#pragma unroll
    for (int j = 0; j < 2; j++) {
        int i = tid + j * 256;
        if (i < 320) *(short8*)(sQ + qp[j] * 40 + qc[j] * 8) = qv[j];
    }
#pragma unroll
    for (int j = 0; j < 4; j++) {
        int i = tid + j * 256;
        if (i < 832) *(short8*)(sK + (i >> 2) * 40 + (i & 3) * 8) = kv[j];
    }
    __syncthreads();

    // ---- QK^T swapped: lane holds S[p=prow][n = nt*16 + quad*4 + r]
    f32x4 s2[13];
    short8 aQ = *(const short8*)(sQ + prow * 40 + quad * 8);
#pragma unroll
    for (int nt = 0; nt < 13; nt++) {
        short8 bK = *(const short8*)(sK + (nt * 16 + l15) * 40 + quad * 8);
        s2[nt] = __builtin_amdgcn_mfma_f32_16x16x32_bf16(bK, aQ, (f32x4){0,0,0,0}, 0, 0, 0);
    }
    __syncthreads();        // sQ/sK dead; region becomes sV

    // ---- scale + bias (nt=12 masks n>=196)
#pragma unroll
    for (int nt = 0; nt < 13; nt++) {
#pragma unroll
        for (int r = 0; r < 4; r++) {
            float v = s2[nt][r] * 0.25f + bi[nt][r];
            if (nt == 12 && (quad * 4 + r) >= 4) v = -1e30f;
            s2[nt][r] = v;
        }
    }

    // ---- issue V loads (land during softmax)
    const short* vg = vT + (long)bh * 13312;
    short8 vv[7]; int vd[7], vc[7];
#pragma unroll
    for (int j = 0; j < 7; j++) {
        int i = tid + j * 256;
        vd[j] = i / 26; vc[j] = i % 26;
        if (i < 1664) vv[j] = *(const short8*)(vg + i * 8);
    }

    // ---- softmax over the lane-resident row
    float m = -3e38f;
#pragma unroll
    for (int nt = 0; nt < 13; nt++)
        m = fmaxf(m, fmaxf(fmaxf(s2[nt][0], s2[nt][1]), fmaxf(s2[nt][2], s2[nt][3])));
    m = fmaxf(m, __shfl_xor(m, 16));
    m = fmaxf(m, __shfl_xor(m, 32));
    float sum = 0.f;
#pragma unroll
    for (int nt = 0; nt < 13; nt++) {
#pragma unroll
        for (int r = 0; r < 4; r++) {
            float e = __expf(s2[nt][r] - m);
            s2[nt][r] = e; sum += e;
        }
    }
    sum += __shfl_xor(sum, 16);
    sum += __shfl_xor(sum, 32);
    float inv = 1.f / sum;

    // ---- stage V (+ zero pad cols 208..223)
#pragma unroll
    for (int j = 0; j < 7; j++) {
        int i = tid + j * 256;
        if (i < 1664) *(short8*)(sV + vd[j] * 232 + vc[j] * 8) = vv[j];
    }
    {
        int d = tid >> 2, c0 = 208 + (tid & 3) * 4;
        *(short4v*)(sV + d * 232 + c0) = (short4v){0,0,0,0};
    }
    __syncthreads();        // sV visible to all waves

    // ---- PV: per-ks wave-private P transpose through sP, K=224
    f32x4 o[4];
#pragma unroll
    for (int dt = 0; dt < 4; dt++) o[dt] = (f32x4){0.f,0.f,0.f,0.f};
#pragma unroll
    for (int ks = 0; ks < 7; ks++) {
        int ntA = 2 * ks;
        short4v w0, w1;
        w0.x = f2bf(s2[ntA][0] * inv); w0.y = f2bf(s2[ntA][1] * inv);
        w0.z = f2bf(s2[ntA][2] * inv); w0.w = f2bf(s2[ntA][3] * inv);
        if (ntA + 1 < 13) {
            w1.x = f2bf(s2[ntA+1][0] * inv); w1.y = f2bf(s2[ntA+1][1] * inv);
            w1.z = f2bf(s2[ntA+1][2] * inv); w1.w = f2bf(s2[ntA+1][3] * inv);
        } else w1 = (short4v){0,0,0,0};
        *(short4v*)(sP + prow * 40 + quad * 4) = w0;
        *(short4v*)(sP + prow * 40 + 16 + quad * 4) = w1;
        short8 aP = *(const short8*)(sP + prow * 40 + quad * 8);
#pragma unroll
        for (int dt = 0; dt < 4; dt++) {
            short8 bV = *(const short8*)(sV + (dt * 16 + l15) * 232 + ks * 32 + quad * 8);
            o[dt] = __builtin_amdgcn_mfma_f32_16x16x32_bf16(aP, bV, o[dt], 0, 0, 0);
        }
    }

    // ---- epilogue: v_local 9-tap from sV + BN + ReLU -> attT
#pragma unroll
    for (int r = 0; r < 4; r++) {
        int p = wave * 16 + quad * 4 + r;
        if (p >= 49) continue;
        int h2 = p / 7, w2 = p % 7;
#pragma unroll
        for (int dt = 0; dt < 4; dt++) {
            int d = dt * 16 + l15, c = h * 64 + d;
            float acc2 = vlb[c];
            const float* wc = vlw + c * 9;
            const short* vrow = sV + d * 232;
#pragma unroll
            for (int kh = 0; kh < 3; kh++) {
                int hin = 2 * h2 - 1 + kh;
                if (hin < 0 || hin >= 14) continue;
#pragma unroll
                for (int kk = 0; kk < 3; kk++) {
                    int win = 2 * w2 - 1 + kk;
                    if (win < 0 || win >= 14) continue;
                    acc2 += u2f((unsigned short)vrow[hin * 14 + win]) * wc[kh * 3 + kk];
                }
            }
            float vl = vlbs[c] * acc2 + vlbb[c];
            attT[((long)b * 64 + p) * 512 + h * 64 + d]
                = f2bf(fmaxf(o[dt][r] + vl, 0.f));
        }
    }
    for (int i = tid; i < 960; i += 256) {   // zero attT rows p 49..63
        int p = 49 + i / 64, d = i % 64;
        attT[((long)b * 64 + p) * 512 + h * 64 + d] = 0;
    }
}

// ---------------------------------------------------------------------------
// out = bn(conv1x1(relu(att))) via MFMA.
__global__ __launch_bounds__(256) void k_pconv_mfma(const short* __restrict__ attT,
        const short* __restrict__ pwb, const float* __restrict__ bias,
        const float* __restrict__ bns, const float* __restrict__ bnb,
        float* __restrict__ out) {
    __shared__ short sA[128 * 72];
    __shared__ short sB[64 * 72];
    int b = blockIdx.y, ocblk = blockIdx.x, tid = threadIdx.x;
    int wave = tid >> 6, lane = tid & 63, quad = lane >> 4, l15 = lane & 15;
    int ocbase = ocblk * 128;

    f32x4 acc[2][4];
#pragma unroll
    for (int t = 0; t < 2; t++)
#pragma unroll
        for (int nt = 0; nt < 4; nt++) acc[t][nt] = (f32x4){0.f,0.f,0.f,0.f};

    for (int ct = 0; ct < 8; ct++) {
        for (int i = tid; i < 1024; i += 256) {
            int r = i >> 3, c8 = i & 7;
            *(short8*)(sA + r * 72 + c8 * 8)
                = *(const short8*)(pwb + (long)(ocbase + r) * 512 + ct * 64 + c8 * 8);
        }
        for (int i = tid; i < 512; i += 256) {
            int r = i >> 3, c8 = i & 7;
            *(short8*)(sB + r * 72 + c8 * 8)
                = *(const short8*)(attT + ((long)b * 64 + r) * 512 + ct * 64 + c8 * 8);
        }
        __syncthreads();
        short8 a00 = *(const short8*)(sA + (wave * 32 + l15) * 72 + quad * 8);
        short8 a01 = *(const short8*)(sA + (wave * 32 + l15) * 72 + 32 + quad * 8);
        short8 a10 = *(const short8*)(sA + (wave * 32 + 16 + l15) * 72 + quad * 8);
        short8 a11 = *(const short8*)(sA + (wave * 32 + 16 + l15) * 72 + 32 + quad * 8);
#pragma unroll
        for (int nt = 0; nt < 4; nt++) {
            short8 b0 = *(const short8*)(sB + (nt * 16 + l15) * 72 + quad * 8);
            short8 b1 = *(const short8*)(sB + (nt * 16 + l15) * 72 + 32 + quad * 8);
            acc[0][nt] = __builtin_amdgcn_mfma_f32_16x16x32_bf16(a00, b0, acc[0][nt], 0, 0, 0);
            acc[0][nt] = __builtin_amdgcn_mfma_f32_16x16x32_bf16(a01, b1, acc[0][nt], 0, 0, 0);
            acc[1][nt] = __builtin_amdgcn_mfma_f32_16x16x32_bf16(a10, b0, acc[1][nt], 0, 0, 0);
            acc[1][nt] = __builtin_amdgcn_mfma_f32_16x16x32_bf16(a11, b1, acc[1][nt], 0, 0, 0);
        }
        __syncthreads();
    }

#pragma unroll
    for (int t = 0; t < 2; t++) {
#pragma unroll
        for (int nt = 0; nt < 4; nt++) {
            int p = nt * 16 + l15;
            if (p >= 49) continue;
#pragma unroll
            for (int r = 0; r < 4; r++) {
                int oc = ocbase + wave * 32 + t * 16 + quad * 4 + r;
                out[((long)b * 384 + oc) * 49 + p]
                    = bns[oc] * (acc[t][nt][r] + bias[oc]) + bnb[oc];
            }
        }
    }
}

// ---------------------------------------------------------------------------
extern "C" void kernel_launch(void* const* d_in, const int* in_sizes, int n_in,
                              void* d_out, int out_size, void* d_ws, size_t ws_size,
                              hipStream_t stream) {
    const float* x    = (const float*)d_in[0];
    const float* qlw  = (const float*)d_in[1];
    const float* qlb  = (const float*)d_in[2];
    const float* qpw  = (const float*)d_in[3];
    const float* qpb  = (const float*)d_in[4];
    const float* qbs  = (const float*)d_in[5];
    const float* qbb  = (const float*)d_in[6];
    const float* kw   = (const float*)d_in[7];
    const float* kb   = (const float*)d_in[8];
    const float* kbs  = (const float*)d_in[9];
    const float* kbb  = (const float*)d_in[10];
    const float* vw   = (const float*)d_in[11];
    const float* vb   = (const float*)d_in[12];
    const float* vbs  = (const float*)d_in[13];
    const float* vbb  = (const float*)d_in[14];
    const float* vlw  = (const float*)d_in[15];
    const float* vlb  = (const float*)d_in[16];
    const float* vlbs = (const float*)d_in[17];
    const float* vlbb = (const float*)d_in[18];
    const float* btab = (const float*)d_in[19];
    const float* pw   = (const float*)d_in[20];
    const float* pb   = (const float*)d_in[21];
    const float* pbs  = (const float*)d_in[22];
    const float* pbb  = (const float*)d_in[23];
    float* out = (float*)d_out;

    char* W = (char*)d_ws;
    short* xT   = (short*)(W + 0);
    short* qinT = (short*)(W + 40894464);     // aliased by attT
    short* attT = (short*)(W + 40894464);
    short* q_t  = (short*)(W + 57671680);
    short* kbf  = (short*)(W + 60882944);
    short* vT   = (short*)(W + 88145920);
    short* wkv  = (short*)(W + 142671872);
    short* pwb  = (short*)(W + 143261696);    // end 143,654,912
    if (ws_size < 143654912) return;

    k_prep      <<<19840, 256, 0, stream>>>(x, qlw, qlb, kw, vw, qpw, pw,
                                            xT, qinT, wkv, pwb);
    k_kv_mfma   <<<dim3(6, 256), 256, 0, stream>>>(wkv, xT, qinT,
                                                   kb, kbs, kbb, vb, vbs, vbb,
                                                   qpb, qbs, qbb, kbf, vT, q_t);
    k_attn      <<< 2048, 256, 0, stream>>>(q_t, kbf, vT, btab,
                                            vlw, vlb, vlbs, vlbb, attT);
    k_pconv_mfma<<<dim3(3, 256), 256, 0, stream>>>(attT, pwb, pb, pbs, pbb, out);
}

// Round 3
// 311.265 us; speedup vs baseline: 1.8005x; 1.6329x over previous
//
#include <hip/hip_runtime.h>
#include <hip/hip_bf16.h>

typedef __hip_bfloat16 bf16;
typedef __attribute__((ext_vector_type(8))) short short8;   // 8 bf16 (4 VGPRs)
typedef __attribute__((ext_vector_type(4))) short short4v;
typedef __attribute__((ext_vector_type(4))) float f32x4;

__device__ __forceinline__ short f2bf(float f) {            // f32 -> bf16 bits
    bf16 h = __float2bfloat16(f);
    return *reinterpret_cast<short*>(&h);
}
__device__ __forceinline__ float u2f(unsigned short u) {    // bf16 bits -> f32
    return __uint_as_float(((unsigned)u) << 16);
}

// Shapes: B=256, C=384, N=196 (14x14), N2=49 (7x7), HEADS=8, KD=16, D=64,
// NHKD=128, DH=512, OUT=384. Inputs fp32, output fp32.
// ws carve (143,654,912 B):
//   xT   bf16 [256][208][384]            @ 0
//   qinT bf16 [256][64][384] (alias attT)@ 40,894,464
//   attT bf16 [256][64][512]             @ 40,894,464
//   q_t  bf16 [256*8][49][16]            @ 57,671,680
//   kbf  bf16 [256*8][208][32]           @ 60,882,944  (kd 16..31 finite junk)
//   vT   bf16 [256*8][64][208]           @ 88,145,920
//   wkv  bf16 [768][384] (k,v,qproj w)   @ 142,671,872
//   pwb  bf16 [384][512]                 @ 143,261,696

// ---------------------------------------------------------------------------
// k_prep: blocks 0..1535  = {x chunk -> LDS fp32 (read ONCE, coalesced);
//                            emit xT bf16 transpose; compute q_local dwconv
//                            + pool -> qinT bf16 for 49 p x 64 c}
//         blocks 1536..3455 = weight cvt to bf16.
__global__ __launch_bounds__(256) void k_prep(const float* __restrict__ x,
        const float* __restrict__ qlw, const float* __restrict__ qlb,
        const float* __restrict__ kw, const float* __restrict__ vw,
        const float* __restrict__ qpw, const float* __restrict__ pw,
        short* __restrict__ xT, short* __restrict__ qinT,
        short* __restrict__ wkv, short* __restrict__ pwb) {
    __shared__ float sX[64 * 197];           // 50,432 B, odd stride (bank-safe)
    int bid = blockIdx.x, tid = threadIdx.x;
    if (bid < 1536) {
        int ct = bid % 6, b = bid / 6;
        // ---- load x[b][ct*64..+64][0..195] fp32, coalesced, once
        for (int i = tid; i < 64 * 196; i += 256) {
            int c = i / 196, n = i % 196;
            sX[c * 197 + n] = x[((long)b * 384 + ct * 64 + c) * 196 + n];
        }
        __syncthreads();
        // ---- xT[b][n][c] = bf16(x[b][c][n]); rows 196..207 zeroed
        for (int i = tid; i < 196 * 64; i += 256) {
            int n = i / 64, c = i % 64;
            xT[((long)b * 208 + n) * 384 + ct * 64 + c] = f2bf(sX[c * 197 + n]);
        }
        for (int i = tid; i < 12 * 64; i += 256) {
            int n = 196 + i / 64, c = i % 64;
            xT[((long)b * 208 + n) * 384 + ct * 64 + c] = 0;
        }
        // ---- qinT: thread owns column c = tid%64; p walks tid/64, +4
        {
            int c = tid & 63;
            int cg = ct * 64 + c;
            const float* wc = qlw + cg * 9;
            float w9[9];
#pragma unroll
            for (int j = 0; j < 9; j++) w9[j] = wc[j];
            float bia = qlb[cg];
            const float* xr = sX + c * 197;
            for (int p = tid >> 6; p < 49; p += 4) {
                int h2 = p / 7, w2 = p % 7;
                float acc = bia;
#pragma unroll
                for (int kh = 0; kh < 3; kh++) {
                    int hin = 2 * h2 - 1 + kh;
                    if (hin < 0 || hin >= 14) continue;
#pragma unroll
                    for (int kk = 0; kk < 3; kk++) {
                        int win = 2 * w2 - 1 + kk;
                        if (win < 0 || win >= 14) continue;
                        acc += xr[hin * 14 + win] * w9[kh * 3 + kk];
                    }
                }
                acc += xr[(2 * h2) * 14 + 2 * w2];
                qinT[((long)b * 64 + p) * 384 + cg] = f2bf(acc);
            }
            // zero qinT rows p 49..63 for this chunk
            for (int p = 49 + (tid >> 6); p < 64; p += 4)
                qinT[((long)b * 64 + p) * 384 + cg] = 0;
        }
    } else {
        // ---- weights -> bf16: wkv = [kw | vw | qpw], pwb = pw
        int idx = (bid - 1536) * 256 + tid;
        if (idx < 294912) {
            float v;
            if (idx < 49152) v = kw[idx];
            else if (idx < 245760) v = vw[idx - 49152];
            else v = qpw[idx - 245760];
            wkv[idx] = f2bf(v);
        } else {
            int j = idx - 294912;
            pwb[j] = f2bf(pw[j]);
        }
    }
}

// ---------------------------------------------------------------------------
// K+V+Q 1x1 convs via MFMA. ocblk 0: K, 1..4: V, 5: Q (B = qinT, 64 rows).
__global__ __launch_bounds__(256) void k_kv_mfma(const short* __restrict__ wkv,
        const short* __restrict__ xT, const short* __restrict__ qinT,
        const float* __restrict__ kb, const float* __restrict__ kbs,
        const float* __restrict__ kbb, const float* __restrict__ vb,
        const float* __restrict__ vbs, const float* __restrict__ vbb,
        const float* __restrict__ qpb, const float* __restrict__ qbs,
        const float* __restrict__ qbb,
        short* __restrict__ kbf, short* __restrict__ vT, short* __restrict__ q_t) {
    __shared__ short sA[128 * 40];       // w: [oc][k32]
    __shared__ short sB[208 * 40];       // x: [n][k32]
    int b = blockIdx.y, ocblk = blockIdx.x, tid = threadIdx.x;
    int wave = tid >> 6, lane = tid & 63, quad = lane >> 4, l15 = lane & 15;

    if (ocblk == 5) {
        // ---------------- Q projection: [128 oc] x [64 p] over K=384
        f32x4 qa[2][4];
#pragma unroll
        for (int t = 0; t < 2; t++)
#pragma unroll
            for (int nt = 0; nt < 4; nt++) qa[t][nt] = (f32x4){0.f,0.f,0.f,0.f};
        for (int ct = 0; ct < 12; ct++) {
#pragma unroll
            for (int j = 0; j < 2; j++) {
                int s = tid + j * 256, r = s >> 2, c = s & 3;
                *(short8*)(sA + r * 40 + c * 8)
                    = *(const short8*)(wkv + (long)(640 + r) * 384 + ct * 32 + c * 8);
            }
            {
                int r = tid >> 2, c = tid & 3;
                *(short8*)(sB + r * 40 + c * 8)
                    = *(const short8*)(qinT + ((long)b * 64 + r) * 384 + ct * 32 + c * 8);
            }
            __syncthreads();
            short8 bw0 = *(const short8*)(sA + (wave * 32 + l15) * 40 + quad * 8);
            short8 bw1 = *(const short8*)(sA + (wave * 32 + 16 + l15) * 40 + quad * 8);
#pragma unroll
            for (int nt = 0; nt < 4; nt++) {
                short8 ax = *(const short8*)(sB + (nt * 16 + l15) * 40 + quad * 8);
                qa[0][nt] = __builtin_amdgcn_mfma_f32_16x16x32_bf16(ax, bw0, qa[0][nt], 0, 0, 0);
                qa[1][nt] = __builtin_amdgcn_mfma_f32_16x16x32_bf16(ax, bw1, qa[1][nt], 0, 0, 0);
            }
            __syncthreads();
        }
#pragma unroll
        for (int t = 0; t < 2; t++) {
            int oc = wave * 32 + t * 16 + l15;          // 0..127
            int hh = oc >> 4, kd = oc & 15;
            float sc = qbs[oc], bi = qpb[oc], bb2 = qbb[oc];
#pragma unroll
            for (int nt = 0; nt < 4; nt++) {
#pragma unroll
                for (int r = 0; r < 4; r++) {
                    int p = nt * 16 + quad * 4 + r;
                    if (p < 49)
                        q_t[(((long)b * 8 + hh) * 49 + p) * 16 + kd]
                            = f2bf(sc * (qa[t][nt][r] + bi) + bb2);
                }
            }
        }
        return;
    }

    // ---------------- K/V path (reg-prefetch, BK=32)
    int ocbase = ocblk * 128;
    f32x4 acc[2][13];
#pragma unroll
    for (int t = 0; t < 2; t++)
#pragma unroll
        for (int nt = 0; nt < 13; nt++) acc[t][nt] = (f32x4){0.f,0.f,0.f,0.f};

    short8 pA[2], pB[4], nA[2], nB[4];
    {
#pragma unroll
        for (int j = 0; j < 2; j++) {
            int s = tid + j * 256, r = s >> 2, c = s & 3;
            pA[j] = *(const short8*)(wkv + (long)(ocbase + r) * 384 + c * 8);
        }
#pragma unroll
        for (int j = 0; j < 4; j++) {
            int s = tid + j * 256;
            if (s < 832) {
                int r = s >> 2, c = s & 3;
                pB[j] = *(const short8*)(xT + ((long)b * 208 + r) * 384 + c * 8);
            }
        }
    }

    for (int ct = 0; ct < 12; ct++) {
#pragma unroll
        for (int j = 0; j < 2; j++) {
            int s = tid + j * 256, r = s >> 2, c = s & 3;
            *(short8*)(sA + r * 40 + c * 8) = pA[j];
        }
#pragma unroll
        for (int j = 0; j < 4; j++) {
            int s = tid + j * 256;
            if (s < 832) {
                int r = s >> 2, c = s & 3;
                *(short8*)(sB + r * 40 + c * 8) = pB[j];
            }
        }
        __syncthreads();
        if (ct < 11) {
            int cn = ct + 1;
#pragma unroll
            for (int j = 0; j < 2; j++) {
                int s = tid + j * 256, r = s >> 2, c = s & 3;
                nA[j] = *(const short8*)(wkv + (long)(ocbase + r) * 384 + cn * 32 + c * 8);
            }
#pragma unroll
            for (int j = 0; j < 4; j++) {
                int s = tid + j * 256;
                if (s < 832) {
                    int r = s >> 2, c = s & 3;
                    nB[j] = *(const short8*)(xT + ((long)b * 208 + r) * 384 + cn * 32 + c * 8);
                }
            }
        }
        short8 bw0 = *(const short8*)(sA + (wave * 32 + l15) * 40 + quad * 8);
        short8 bw1 = *(const short8*)(sA + (wave * 32 + 16 + l15) * 40 + quad * 8);
#pragma unroll
        for (int nt = 0; nt < 13; nt++) {
            short8 ax = *(const short8*)(sB + (nt * 16 + l15) * 40 + quad * 8);
            acc[0][nt] = __builtin_amdgcn_mfma_f32_16x16x32_bf16(ax, bw0, acc[0][nt], 0, 0, 0);
            acc[1][nt] = __builtin_amdgcn_mfma_f32_16x16x32_bf16(ax, bw1, acc[1][nt], 0, 0, 0);
        }
        __syncthreads();
#pragma unroll
        for (int j = 0; j < 2; j++) pA[j] = nA[j];
#pragma unroll
        for (int j = 0; j < 4; j++) pB[j] = nB[j];
    }

    // epilogue: row (quad*4+r) = n (ALL n 0..207 stored, pads finite), col = oc
#pragma unroll
    for (int t = 0; t < 2; t++) {
        int oc = ocbase + wave * 32 + t * 16 + l15;
        if (ocblk == 0) {                             // K outputs (oc < 128)
            int hh = oc >> 4, kd = oc & 15;
            float sc = kbs[oc], bi = kb[oc], bb2 = kbb[oc];
            short* kbase = kbf + ((long)(b * 8 + hh) * 208) * 32 + kd;
#pragma unroll
            for (int nt = 0; nt < 13; nt++) {
                int n0 = nt * 16 + quad * 4;
#pragma unroll
                for (int r = 0; r < 4; r++)
                    kbase[(long)(n0 + r) * 32] = f2bf(sc * (acc[t][nt][r] + bi) + bb2);
            }
        } else {                                      // V outputs
            int cc = oc - 128, hh = cc >> 6, d = cc & 63;
            float sc = vbs[cc], bi = vb[cc], bb2 = vbb[cc];
            short* vbase = vT + ((long)(b * 8 + hh) * 64 + d) * 208;
#pragma unroll
            for (int nt = 0; nt < 13; nt++) {
                int n0 = nt * 16 + quad * 4;
                short4v ov;
                ov.x = f2bf(sc * (acc[t][nt][0] + bi) + bb2);
                ov.y = f2bf(sc * (acc[t][nt][1] + bi) + bb2);
                ov.z = f2bf(sc * (acc[t][nt][2] + bi) + bb2);
                ov.w = f2bf(sc * (acc[t][nt][3] + bi) + bb2);
                *(short4v*)(vbase + n0) = ov;
            }
        }
    }
}

// ---------------------------------------------------------------------------
// attention per (b,h), swapped-operand QK^T: s2 = mfma(K,Q) puts a full
// softmax row in each lane (in-lane reduce + 2 shuffles). bias_tab loaded as
// 13 f32x4 at kernel start; V loads issued under softmax, staged to LDS
// (stride 232). P transposed for PV via a 5KB wave-private per-ks LDS tile
// (DS per-wave FIFO => no barrier). 34.8KB LDS -> 4 blocks/CU.
__global__ __launch_bounds__(256, 3) void k_attn(const short* __restrict__ q_t,
        const short* __restrict__ kbf, const short* __restrict__ vT,
        const float* __restrict__ bias_tab,
        const float* __restrict__ vlw, const float* __restrict__ vlb,
        const float* __restrict__ vlbs, const float* __restrict__ vlbb,
        short* __restrict__ attT) {
    __shared__ short smem[17408];            // 34,816 B
    short* sQ = smem;                        // [64][40] phase A
    short* sK = smem + 2560;                 // [208][40] phase A
    short* sV = smem;                        // [64][232] phase B (alias A)
    short* sP = smem + 14848;                // [64][40] per-ks P tile
    int bh = blockIdx.x, b = bh >> 3, h = bh & 7, tid = threadIdx.x;
    int wave = tid >> 6, lane = tid & 63, quad = lane >> 4, l15 = lane & 15;
    int prow = wave * 16 + l15;

    // ---- issue Q, K, bias loads (all independent)
    const short8* qg8 = (const short8*)(q_t + (long)bh * 784);
    short8 qv[2]; int qp[2], qc[2];
#pragma unroll
    for (int j = 0; j < 2; j++) {
        int i = tid + j * 256;
        qp[j] = i / 5; qc[j] = i % 5;
        qv[j] = (short8){0,0,0,0,0,0,0,0};
        if (i < 320 && qp[j] < 49 && qc[j] < 2) qv[j] = qg8[qp[j] * 2 + qc[j]];
    }
    const short8* kg8 = (const short8*)(kbf + (long)bh * 6656);
    short8 kv[4];
#pragma unroll
    for (int j = 0; j < 4; j++) {
        int i = tid + j * 256;
        if (i < 832) kv[j] = kg8[i];
    }
    int pb = prow < 49 ? prow : 48;
    const float* bp = bias_tab + ((long)(h * 49 + pb) * 196 + quad * 4);
    f32x4 bi[13];
#pragma unroll
    for (int nt = 0; nt < 13; nt++) bi[nt] = *(const f32x4*)(bp + nt * 16);

    // ---- stage Q, K
#pragma unroll
    for (int j = 0; j < 2; j++) {
        int i = tid + j * 256;
        if (i < 320) *(short8*)(sQ + qp[j] * 40 + qc[j] * 8) = qv[j];
    }
#pragma unroll
    for (int j = 0; j < 4; j++) {
        int i = tid + j * 256;
        if (i < 832) *(short8*)(sK + (i >> 2) * 40 + (i & 3) * 8) = kv[j];
    }
    __syncthreads();

    // ---- QK^T swapped: lane holds S[p=prow][n = nt*16 + quad*4 + r]
    f32x4 s2[13];
    short8 aQ = *(const short8*)(sQ + prow * 40 + quad * 8);
#pragma unroll
    for (int nt = 0; nt < 13; nt++) {
        short8 bK = *(const short8*)(sK + (nt * 16 + l15) * 40 + quad * 8);
        s2[nt] = __builtin_amdgcn_mfma_f32_16x16x32_bf16(bK, aQ, (f32x4){0,0,0,0}, 0, 0, 0);
    }
    __syncthreads();        // sQ/sK dead; region becomes sV

    // ---- scale + bias (nt=12 masks n>=196)
#pragma unroll
    for (int nt = 0; nt < 13; nt++) {
#pragma unroll
        for (int r = 0; r < 4; r++) {
            float v = s2[nt][r] * 0.25f + bi[nt][r];
            if (nt == 12 && (quad * 4 + r) >= 4) v = -1e30f;
            s2[nt][r] = v;
        }
    }

    // ---- issue V loads (land during softmax)
    const short* vg = vT + (long)bh * 13312;
    short8 vv[7]; int vd[7], vc[7];
#pragma unroll
    for (int j = 0; j < 7; j++) {
        int i = tid + j * 256;
        vd[j] = i / 26; vc[j] = i % 26;
        if (i < 1664) vv[j] = *(const short8*)(vg + i * 8);
    }

    // ---- softmax over the lane-resident row
    float m = -3e38f;
#pragma unroll
    for (int nt = 0; nt < 13; nt++)
        m = fmaxf(m, fmaxf(fmaxf(s2[nt][0], s2[nt][1]), fmaxf(s2[nt][2], s2[nt][3])));
    m = fmaxf(m, __shfl_xor(m, 16));
    m = fmaxf(m, __shfl_xor(m, 32));
    float sum = 0.f;
#pragma unroll
    for (int nt = 0; nt < 13; nt++) {
#pragma unroll
        for (int r = 0; r < 4; r++) {
            float e = __expf(s2[nt][r] - m);
            s2[nt][r] = e; sum += e;
        }
    }
    sum += __shfl_xor(sum, 16);
    sum += __shfl_xor(sum, 32);
    float inv = 1.f / sum;

    // ---- stage V (+ zero pad cols 208..223)
#pragma unroll
    for (int j = 0; j < 7; j++) {
        int i = tid + j * 256;
        if (i < 1664) *(short8*)(sV + vd[j] * 232 + vc[j] * 8) = vv[j];
    }
    {
        int d = tid >> 2, c0 = 208 + (tid & 3) * 4;
        *(short4v*)(sV + d * 232 + c0) = (short4v){0,0,0,0};
    }
    __syncthreads();        // sV visible to all waves

    // ---- PV: per-ks wave-private P transpose through sP, K=224
    f32x4 o[4];
#pragma unroll
    for (int dt = 0; dt < 4; dt++) o[dt] = (f32x4){0.f,0.f,0.f,0.f};
#pragma unroll
    for (int ks = 0; ks < 7; ks++) {
        int ntA = 2 * ks;
        short4v w0, w1;
        w0.x = f2bf(s2[ntA][0] * inv); w0.y = f2bf(s2[ntA][1] * inv);
        w0.z = f2bf(s2[ntA][2] * inv); w0.w = f2bf(s2[ntA][3] * inv);
        if (ntA + 1 < 13) {
            w1.x = f2bf(s2[ntA+1][0] * inv); w1.y = f2bf(s2[ntA+1][1] * inv);
            w1.z = f2bf(s2[ntA+1][2] * inv); w1.w = f2bf(s2[ntA+1][3] * inv);
        } else w1 = (short4v){0,0,0,0};
        *(short4v*)(sP + prow * 40 + quad * 4) = w0;
        *(short4v*)(sP + prow * 40 + 16 + quad * 4) = w1;
        short8 aP = *(const short8*)(sP + prow * 40 + quad * 8);
#pragma unroll
        for (int dt = 0; dt < 4; dt++) {
            short8 bV = *(const short8*)(sV + (dt * 16 + l15) * 232 + ks * 32 + quad * 8);
            o[dt] = __builtin_amdgcn_mfma_f32_16x16x32_bf16(aP, bV, o[dt], 0, 0, 0);
        }
    }

    // ---- epilogue: v_local 9-tap from sV + BN + ReLU -> attT
#pragma unroll
    for (int r = 0; r < 4; r++) {
        int p = wave * 16 + quad * 4 + r;
        if (p >= 49) continue;
        int h2 = p / 7, w2 = p % 7;
#pragma unroll
        for (int dt = 0; dt < 4; dt++) {
            int d = dt * 16 + l15, c = h * 64 + d;
            float acc2 = vlb[c];
            const float* wc = vlw + c * 9;
            const short* vrow = sV + d * 232;
#pragma unroll
            for (int kh = 0; kh < 3; kh++) {
                int hin = 2 * h2 - 1 + kh;
                if (hin < 0 || hin >= 14) continue;
#pragma unroll
                for (int kk = 0; kk < 3; kk++) {
                    int win = 2 * w2 - 1 + kk;
                    if (win < 0 || win >= 14) continue;
                    acc2 += u2f((unsigned short)vrow[hin * 14 + win]) * wc[kh * 3 + kk];
                }
            }
            float vl = vlbs[c] * acc2 + vlbb[c];
            attT[((long)b * 64 + p) * 512 + h * 64 + d]
                = f2bf(fmaxf(o[dt][r] + vl, 0.f));
        }
    }
    for (int i = tid; i < 960; i += 256) {   // zero attT rows p 49..63
        int p = 49 + i / 64, d = i % 64;
        attT[((long)b * 64 + p) * 512 + h * 64 + d] = 0;
    }
}

// ---------------------------------------------------------------------------
// out = bn(conv1x1(relu(att))) via MFMA.
__global__ __launch_bounds__(256) void k_pconv_mfma(const short* __restrict__ attT,
        const short* __restrict__ pwb, const float* __restrict__ bias,
        const float* __restrict__ bns, const float* __restrict__ bnb,
        float* __restrict__ out) {
    __shared__ short sA[128 * 72];
    __shared__ short sB[64 * 72];
    int b = blockIdx.y, ocblk = blockIdx.x, tid = threadIdx.x;
    int wave = tid >> 6, lane = tid & 63, quad = lane >> 4, l15 = lane & 15;
    int ocbase = ocblk * 128;

    f32x4 acc[2][4];
#pragma unroll
    for (int t = 0; t < 2; t++)
#pragma unroll
        for (int nt = 0; nt < 4; nt++) acc[t][nt] = (f32x4){0.f,0.f,0.f,0.f};

    for (int ct = 0; ct < 8; ct++) {
        for (int i = tid; i < 1024; i += 256) {
            int r = i >> 3, c8 = i & 7;
            *(short8*)(sA + r * 72 + c8 * 8)
                = *(const short8*)(pwb + (long)(ocbase + r) * 512 + ct * 64 + c8 * 8);
        }
        for (int i = tid; i < 512; i += 256) {
            int r = i >> 3, c8 = i & 7;
            *(short8*)(sB + r * 72 + c8 * 8)
                = *(const short8*)(attT + ((long)b * 64 + r) * 512 + ct * 64 + c8 * 8);
        }
        __syncthreads();
        short8 a00 = *(const short8*)(sA + (wave * 32 + l15) * 72 + quad * 8);
        short8 a01 = *(const short8*)(sA + (wave * 32 + l15) * 72 + 32 + quad * 8);
        short8 a10 = *(const short8*)(sA + (wave * 32 + 16 + l15) * 72 + quad * 8);
        short8 a11 = *(const short8*)(sA + (wave * 32 + 16 + l15) * 72 + 32 + quad * 8);
#pragma unroll
        for (int nt = 0; nt < 4; nt++) {
            short8 b0 = *(const short8*)(sB + (nt * 16 + l15) * 72 + quad * 8);
            short8 b1 = *(const short8*)(sB + (nt * 16 + l15) * 72 + 32 + quad * 8);
            acc[0][nt] = __builtin_amdgcn_mfma_f32_16x16x32_bf16(a00, b0, acc[0][nt], 0, 0, 0);
            acc[0][nt] = __builtin_amdgcn_mfma_f32_16x16x32_bf16(a01, b1, acc[0][nt], 0, 0, 0);
            acc[1][nt] = __builtin_amdgcn_mfma_f32_16x16x32_bf16(a10, b0, acc[1][nt], 0, 0, 0);
            acc[1][nt] = __builtin_amdgcn_mfma_f32_16x16x32_bf16(a11, b1, acc[1][nt], 0, 0, 0);
        }
        __syncthreads();
    }

#pragma unroll
    for (int t = 0; t < 2; t++) {
#pragma unroll
        for (int nt = 0; nt < 4; nt++) {
            int p = nt * 16 + l15;
            if (p >= 49) continue;
#pragma unroll
            for (int r = 0; r < 4; r++) {
                int oc = ocbase + wave * 32 + t * 16 + quad * 4 + r;
                out[((long)b * 384 + oc) * 49 + p]
                    = bns[oc] * (acc[t][nt][r] + bias[oc]) + bnb[oc];
            }
        }
    }
}

// ---------------------------------------------------------------------------
extern "C" void kernel_launch(void* const* d_in, const int* in_sizes, int n_in,
                              void* d_out, int out_size, void* d_ws, size_t ws_size,
                              hipStream_t stream) {
    const float* x    = (const float*)d_in[0];
    const float* qlw  = (const float*)d_in[1];
    const float* qlb  = (const float*)d_in[2];
    const float* qpw  = (const float*)d_in[3];
    const float* qpb  = (const float*)d_in[4];
    const float* qbs  = (const float*)d_in[5];
    const float* qbb  = (const float*)d_in[6];
    const float* kw   = (const float*)d_in[7];
    const float* kb   = (const float*)d_in[8];
    const float* kbs  = (const float*)d_in[9];
    const float* kbb  = (const float*)d_in[10];
    const float* vw   = (const float*)d_in[11];
    const float* vb   = (const float*)d_in[12];
    const float* vbs  = (const float*)d_in[13];
    const float* vbb  = (const float*)d_in[14];
    const float* vlw  = (const float*)d_in[15];
    const float* vlb  = (const float*)d_in[16];
    const float* vlbs = (const float*)d_in[17];
    const float* vlbb = (const float*)d_in[18];
    const float* btab = (const float*)d_in[19];
    const float* pw   = (const float*)d_in[20];
    const float* pb   = (const float*)d_in[21];
    const float* pbs  = (const float*)d_in[22];
    const float* pbb  = (const float*)d_in[23];
    float* out = (float*)d_out;

    char* W = (char*)d_ws;
    short* xT   = (short*)(W + 0);
    short* qinT = (short*)(W + 40894464);     // aliased by attT
    short* attT = (short*)(W + 40894464);
    short* q_t  = (short*)(W + 57671680);
    short* kbf  = (short*)(W + 60882944);
    short* vT   = (short*)(W + 88145920);
    short* wkv  = (short*)(W + 142671872);
    short* pwb  = (short*)(W + 143261696);    // end 143,654,912
    if (ws_size < 143654912) return;

    k_prep      <<< 3456, 256, 0, stream>>>(x, qlw, qlb, kw, vw, qpw, pw,
                                            xT, qinT, wkv, pwb);
    k_kv_mfma   <<<dim3(6, 256), 256, 0, stream>>>(wkv, xT, qinT,
                                                   kb, kbs, kbb, vb, vbs, vbb,
                                                   qpb, qbs, qbb, kbf, vT, q_t);
    k_attn      <<< 2048, 256, 0, stream>>>(q_t, kbf, vT, btab,
                                            vlw, vlb, vlbs, vlbb, attT);
    k_pconv_mfma<<<dim3(3, 256), 256, 0, stream>>>(attT, pwb, pb, pbs, pbb, out);
}

// Round 4
// 307.648 us; speedup vs baseline: 1.8217x; 1.0118x over previous
//
#include <hip/hip_runtime.h>
#include <hip/hip_bf16.h>

typedef __hip_bfloat16 bf16;
typedef __attribute__((ext_vector_type(8))) short short8;   // 8 bf16 (4 VGPRs)
typedef __attribute__((ext_vector_type(4))) short short4v;
typedef __attribute__((ext_vector_type(4))) float f32x4;

__device__ __forceinline__ short f2bf(float f) {            // f32 -> bf16 bits
    bf16 h = __float2bfloat16(f);
    return *reinterpret_cast<short*>(&h);
}
__device__ __forceinline__ float u2f(unsigned short u) {    // bf16 bits -> f32
    return __uint_as_float(((unsigned)u) << 16);
}

// Shapes: B=256, C=384, N=196 (14x14), N2=49 (7x7), HEADS=8, KD=16, D=64,
// NHKD=128, DH=512, OUT=384. Inputs fp32, output fp32.
// ws carve (143,654,912 B):
//   xT   bf16 [256][208][384]            @ 0
//   qinT bf16 [256][64][384] (alias attT)@ 40,894,464
//   attT bf16 [256][64][512]             @ 40,894,464
//   q_t  bf16 [256*8][49][16]            @ 57,671,680
//   kbf  bf16 [256*8][208][32]           @ 60,882,944  (kd 16..31 finite junk)
//   vT   bf16 [256*8][64][208]           @ 88,145,920
//   wkv  bf16 [768][384] (k,v,qproj w)   @ 142,671,872
//   pwb  bf16 [384][512]                 @ 143,261,696

// ---------------------------------------------------------------------------
// k_prep: blocks 0..1535  = {x chunk -> LDS fp32 (f32x4 coalesced, once);
//                            emit xT bf16 transpose (short8 stores); compute
//                            q_local dwconv + pool -> qinT bf16}
//         blocks 1536..3455 = weight cvt to bf16.
__global__ __launch_bounds__(256) void k_prep(const float* __restrict__ x,
        const float* __restrict__ qlw, const float* __restrict__ qlb,
        const float* __restrict__ kw, const float* __restrict__ vw,
        const float* __restrict__ qpw, const float* __restrict__ pw,
        short* __restrict__ xT, short* __restrict__ qinT,
        short* __restrict__ wkv, short* __restrict__ pwb) {
    __shared__ float sX[64 * 197];           // 50,432 B, stride 197 (coprime)
    int bid = blockIdx.x, tid = threadIdx.x;
    if (bid < 1536) {
        int ct = bid % 6, b = bid / 6;
        // ---- load x[b][ct*64..+64][0..195] as f32x4, coalesced, once
        const float* xb = x + ((long)b * 384 + ct * 64) * 196;
        for (int i = tid; i < 64 * 49; i += 256) {
            int c = i / 49, n4 = i % 49;
            f32x4 v = *(const f32x4*)(xb + c * 196 + n4 * 4);
            float* d = sX + c * 197 + n4 * 4;
            d[0] = v[0]; d[1] = v[1]; d[2] = v[2]; d[3] = v[3];
        }
        __syncthreads();
        // ---- xT[b][n][c] = bf16(x[b][c][n]); short8 stores; rows 196..207 zero
        for (int i = tid; i < 196 * 8; i += 256) {
            int n = i >> 3, c0 = (i & 7) * 8;
            short8 o;
#pragma unroll
            for (int j = 0; j < 8; j++) o[j] = f2bf(sX[(c0 + j) * 197 + n]);
            *(short8*)(xT + ((long)b * 208 + n) * 384 + ct * 64 + c0) = o;
        }
        for (int i = tid; i < 12 * 8; i += 256) {
            int n = 196 + (i >> 3), c0 = (i & 7) * 8;
            *(short8*)(xT + ((long)b * 208 + n) * 384 + ct * 64 + c0)
                = (short8){0,0,0,0,0,0,0,0};
        }
        // ---- qinT: thread owns column c = tid%64; p walks tid/64, +4
        {
            int c = tid & 63;
            int cg = ct * 64 + c;
            const float* wc = qlw + cg * 9;
            float w9[9];
#pragma unroll
            for (int j = 0; j < 9; j++) w9[j] = wc[j];
            float bia = qlb[cg];
            const float* xr = sX + c * 197;
            for (int p = tid >> 6; p < 49; p += 4) {
                int h2 = p / 7, w2 = p % 7;
                float acc = bia;
#pragma unroll
                for (int kh = 0; kh < 3; kh++) {
                    int hin = 2 * h2 - 1 + kh;
                    if (hin < 0 || hin >= 14) continue;
#pragma unroll
                    for (int kk = 0; kk < 3; kk++) {
                        int win = 2 * w2 - 1 + kk;
                        if (win < 0 || win >= 14) continue;
                        acc += xr[hin * 14 + win] * w9[kh * 3 + kk];
                    }
                }
                acc += xr[(2 * h2) * 14 + 2 * w2];
                qinT[((long)b * 64 + p) * 384 + cg] = f2bf(acc);
            }
            for (int p = 49 + (tid >> 6); p < 64; p += 4)
                qinT[((long)b * 64 + p) * 384 + cg] = 0;
        }
    } else {
        // ---- weights -> bf16: wkv = [kw | vw | qpw], pwb = pw
        int idx = (bid - 1536) * 256 + tid;
        if (idx < 294912) {
            float v;
            if (idx < 49152) v = kw[idx];
            else if (idx < 245760) v = vw[idx - 49152];
            else v = qpw[idx - 245760];
            wkv[idx] = f2bf(v);
        } else {
            int j = idx - 294912;
            pwb[j] = f2bf(pw[j]);
        }
    }
}

// ---------------------------------------------------------------------------
// K+V+Q 1x1 convs via MFMA. Work decode is XCD-grouped: all 6 ocblks of one
// b land on the SAME XCD (private L2) so the 160KB xT slab is HBM-fetched
// once and L2-hit 5x. ocblk 0: K, 1..4: V, 5: Q (B = qinT, 64 rows).
__global__ __launch_bounds__(256) void k_kv_mfma(const short* __restrict__ wkv,
        const short* __restrict__ xT, const short* __restrict__ qinT,
        const float* __restrict__ kb, const float* __restrict__ kbs,
        const float* __restrict__ kbb, const float* __restrict__ vb,
        const float* __restrict__ vbs, const float* __restrict__ vbb,
        const float* __restrict__ qpb, const float* __restrict__ qbs,
        const float* __restrict__ qbb,
        short* __restrict__ kbf, short* __restrict__ vT, short* __restrict__ q_t) {
    __shared__ short sA[128 * 40];       // w: [oc][k32]
    __shared__ short sB[208 * 40];       // x: [n][k32]
    int bid = blockIdx.x, tid = threadIdx.x;
    int tt = bid >> 3;
    int b = (bid & 7) * 32 + tt / 6;     // 1536 = 8 XCD * 32 b * 6 ocblk
    int ocblk = tt % 6;
    int wave = tid >> 6, lane = tid & 63, quad = lane >> 4, l15 = lane & 15;

    if (ocblk == 5) {
        // ---------------- Q projection: [128 oc] x [64 p] over K=384
        f32x4 qa[2][4];
#pragma unroll
        for (int t = 0; t < 2; t++)
#pragma unroll
            for (int nt = 0; nt < 4; nt++) qa[t][nt] = (f32x4){0.f,0.f,0.f,0.f};
        for (int ct = 0; ct < 12; ct++) {
#pragma unroll
            for (int j = 0; j < 2; j++) {
                int s = tid + j * 256, r = s >> 2, c = s & 3;
                *(short8*)(sA + r * 40 + c * 8)
                    = *(const short8*)(wkv + (long)(640 + r) * 384 + ct * 32 + c * 8);
            }
            {
                int r = tid >> 2, c = tid & 3;
                *(short8*)(sB + r * 40 + c * 8)
                    = *(const short8*)(qinT + ((long)b * 64 + r) * 384 + ct * 32 + c * 8);
            }
            __syncthreads();
            short8 bw0 = *(const short8*)(sA + (wave * 32 + l15) * 40 + quad * 8);
            short8 bw1 = *(const short8*)(sA + (wave * 32 + 16 + l15) * 40 + quad * 8);
#pragma unroll
            for (int nt = 0; nt < 4; nt++) {
                short8 ax = *(const short8*)(sB + (nt * 16 + l15) * 40 + quad * 8);
                qa[0][nt] = __builtin_amdgcn_mfma_f32_16x16x32_bf16(ax, bw0, qa[0][nt], 0, 0, 0);
                qa[1][nt] = __builtin_amdgcn_mfma_f32_16x16x32_bf16(ax, bw1, qa[1][nt], 0, 0, 0);
            }
            __syncthreads();
        }
#pragma unroll
        for (int t = 0; t < 2; t++) {
            int oc = wave * 32 + t * 16 + l15;          // 0..127
            int hh = oc >> 4, kd = oc & 15;
            float sc = qbs[oc], bi = qpb[oc], bb2 = qbb[oc];
#pragma unroll
            for (int nt = 0; nt < 4; nt++) {
#pragma unroll
                for (int r = 0; r < 4; r++) {
                    int p = nt * 16 + quad * 4 + r;
                    if (p < 49)
                        q_t[(((long)b * 8 + hh) * 49 + p) * 16 + kd]
                            = f2bf(sc * (qa[t][nt][r] + bi) + bb2);
                }
            }
        }
        return;
    }

    // ---------------- K/V path (reg-prefetch, BK=32)
    int ocbase = ocblk * 128;
    f32x4 acc[2][13];
#pragma unroll
    for (int t = 0; t < 2; t++)
#pragma unroll
        for (int nt = 0; nt < 13; nt++) acc[t][nt] = (f32x4){0.f,0.f,0.f,0.f};

    short8 pA[2], pB[4], nA[2], nB[4];
    {
#pragma unroll
        for (int j = 0; j < 2; j++) {
            int s = tid + j * 256, r = s >> 2, c = s & 3;
            pA[j] = *(const short8*)(wkv + (long)(ocbase + r) * 384 + c * 8);
        }
#pragma unroll
        for (int j = 0; j < 4; j++) {
            int s = tid + j * 256;
            if (s < 832) {
                int r = s >> 2, c = s & 3;
                pB[j] = *(const short8*)(xT + ((long)b * 208 + r) * 384 + c * 8);
            }
        }
    }

    for (int ct = 0; ct < 12; ct++) {
#pragma unroll
        for (int j = 0; j < 2; j++) {
            int s = tid + j * 256, r = s >> 2, c = s & 3;
            *(short8*)(sA + r * 40 + c * 8) = pA[j];
        }
#pragma unroll
        for (int j = 0; j < 4; j++) {
            int s = tid + j * 256;
            if (s < 832) {
                int r = s >> 2, c = s & 3;
                *(short8*)(sB + r * 40 + c * 8) = pB[j];
            }
        }
        __syncthreads();
        if (ct < 11) {
            int cn = ct + 1;
#pragma unroll
            for (int j = 0; j < 2; j++) {
                int s = tid + j * 256, r = s >> 2, c = s & 3;
                nA[j] = *(const short8*)(wkv + (long)(ocbase + r) * 384 + cn * 32 + c * 8);
            }
#pragma unroll
            for (int j = 0; j < 4; j++) {
                int s = tid + j * 256;
                if (s < 832) {
                    int r = s >> 2, c = s & 3;
                    nB[j] = *(const short8*)(xT + ((long)b * 208 + r) * 384 + cn * 32 + c * 8);
                }
            }
        }
        short8 bw0 = *(const short8*)(sA + (wave * 32 + l15) * 40 + quad * 8);
        short8 bw1 = *(const short8*)(sA + (wave * 32 + 16 + l15) * 40 + quad * 8);
#pragma unroll
        for (int nt = 0; nt < 13; nt++) {
            short8 ax = *(const short8*)(sB + (nt * 16 + l15) * 40 + quad * 8);
            acc[0][nt] = __builtin_amdgcn_mfma_f32_16x16x32_bf16(ax, bw0, acc[0][nt], 0, 0, 0);
            acc[1][nt] = __builtin_amdgcn_mfma_f32_16x16x32_bf16(ax, bw1, acc[1][nt], 0, 0, 0);
        }
        __syncthreads();
#pragma unroll
        for (int j = 0; j < 2; j++) pA[j] = nA[j];
#pragma unroll
        for (int j = 0; j < 4; j++) pB[j] = nB[j];
    }

    // epilogue: row (quad*4+r) = n (ALL n 0..207 stored, pads finite), col = oc
#pragma unroll
    for (int t = 0; t < 2; t++) {
        int oc = ocbase + wave * 32 + t * 16 + l15;
        if (ocblk == 0) {                             // K outputs (oc < 128)
            int hh = oc >> 4, kd = oc & 15;
            float sc = kbs[oc], bi = kb[oc], bb2 = kbb[oc];
            short* kbase = kbf + ((long)(b * 8 + hh) * 208) * 32 + kd;
#pragma unroll
            for (int nt = 0; nt < 13; nt++) {
                int n0 = nt * 16 + quad * 4;
#pragma unroll
                for (int r = 0; r < 4; r++)
                    kbase[(long)(n0 + r) * 32] = f2bf(sc * (acc[t][nt][r] + bi) + bb2);
            }
        } else {                                      // V outputs
            int cc = oc - 128, hh = cc >> 6, d = cc & 63;
            float sc = vbs[cc], bi = vb[cc], bb2 = vbb[cc];
            short* vbase = vT + ((long)(b * 8 + hh) * 64 + d) * 208;
#pragma unroll
            for (int nt = 0; nt < 13; nt++) {
                int n0 = nt * 16 + quad * 4;
                short4v ov;
                ov.x = f2bf(sc * (acc[t][nt][0] + bi) + bb2);
                ov.y = f2bf(sc * (acc[t][nt][1] + bi) + bb2);
                ov.z = f2bf(sc * (acc[t][nt][2] + bi) + bb2);
                ov.w = f2bf(sc * (acc[t][nt][3] + bi) + bb2);
                *(short4v*)(vbase + n0) = ov;
            }
        }
    }
}

// ---------------------------------------------------------------------------
// attention per (b,h), swapped-operand QK^T: s2 = mfma(K,Q) puts a full
// softmax row in each lane (in-lane reduce + 2 shuffles). bias_tab loaded as
// 13 f32x4 at kernel start; V loads issued under softmax, staged to LDS
// (stride 232). P transposed for PV via a 5KB wave-private per-ks LDS tile
// (DS per-wave FIFO => no barrier). 34.8KB LDS -> 4 blocks/CU.
__global__ __launch_bounds__(256, 3) void k_attn(const short* __restrict__ q_t,
        const short* __restrict__ kbf, const short* __restrict__ vT,
        const float* __restrict__ bias_tab,
        const float* __restrict__ vlw, const float* __restrict__ vlb,
        const float* __restrict__ vlbs, const float* __restrict__ vlbb,
        short* __restrict__ attT) {
    __shared__ short smem[17408];            // 34,816 B
    short* sQ = smem;                        // [64][40] phase A
    short* sK = smem + 2560;                 // [208][40] phase A
    short* sV = smem;                        // [64][232] phase B (alias A)
    short* sP = smem + 14848;                // [64][40] per-ks P tile
    int bh = blockIdx.x, b = bh >> 3, h = bh & 7, tid = threadIdx.x;
    int wave = tid >> 6, lane = tid & 63, quad = lane >> 4, l15 = lane & 15;
    int prow = wave * 16 + l15;

    // ---- issue Q, K, bias loads (all independent)
    const short8* qg8 = (const short8*)(q_t + (long)bh * 784);
    short8 qv[2]; int qp[2], qc[2];
#pragma unroll
    for (int j = 0; j < 2; j++) {
        int i = tid + j * 256;
        qp[j] = i / 5; qc[j] = i % 5;
        qv[j] = (short8){0,0,0,0,0,0,0,0};
        if (i < 320 && qp[j] < 49 && qc[j] < 2) qv[j] = qg8[qp[j] * 2 + qc[j]];
    }
    const short8* kg8 = (const short8*)(kbf + (long)bh * 6656);
    short8 kv[4];
#pragma unroll
    for (int j = 0; j < 4; j++) {
        int i = tid + j * 256;
        if (i < 832) kv[j] = kg8[i];
    }
    int pb = prow < 49 ? prow : 48;
    const float* bp = bias_tab + ((long)(h * 49 + pb) * 196 + quad * 4);
    f32x4 bi[13];
#pragma unroll
    for (int nt = 0; nt < 13; nt++) bi[nt] = *(const f32x4*)(bp + nt * 16);

    // ---- stage Q, K
#pragma unroll
    for (int j = 0; j < 2; j++) {
        int i = tid + j * 256;
        if (i < 320) *(short8*)(sQ + qp[j] * 40 + qc[j] * 8) = qv[j];
    }
#pragma unroll
    for (int j = 0; j < 4; j++) {
        int i = tid + j * 256;
        if (i < 832) *(short8*)(sK + (i >> 2) * 40 + (i & 3) * 8) = kv[j];
    }
    __syncthreads();

    // ---- QK^T swapped: lane holds S[p=prow][n = nt*16 + quad*4 + r]
    f32x4 s2[13];
    short8 aQ = *(const short8*)(sQ + prow * 40 + quad * 8);
#pragma unroll
    for (int nt = 0; nt < 13; nt++) {
        short8 bK = *(const short8*)(sK + (nt * 16 + l15) * 40 + quad * 8);
        s2[nt] = __builtin_amdgcn_mfma_f32_16x16x32_bf16(bK, aQ, (f32x4){0,0,0,0}, 0, 0, 0);
    }
    __syncthreads();        // sQ/sK dead; region becomes sV

    // ---- scale + bias (nt=12 masks n>=196)
#pragma unroll
    for (int nt = 0; nt < 13; nt++) {
#pragma unroll
        for (int r = 0; r < 4; r++) {
            float v = s2[nt][r] * 0.25f + bi[nt][r];
            if (nt == 12 && (quad * 4 + r) >= 4) v = -1e30f;
            s2[nt][r] = v;
        }
    }

    // ---- issue V loads (land during softmax)
    const short* vg = vT + (long)bh * 13312;
    short8 vv[7]; int vd[7], vc[7];
#pragma unroll
    for (int j = 0; j < 7; j++) {
        int i = tid + j * 256;
        vd[j] = i / 26; vc[j] = i % 26;
        if (i < 1664) vv[j] = *(const short8*)(vg + i * 8);
    }

    // ---- softmax over the lane-resident row
    float m = -3e38f;
#pragma unroll
    for (int nt = 0; nt < 13; nt++)
        m = fmaxf(m, fmaxf(fmaxf(s2[nt][0], s2[nt][1]), fmaxf(s2[nt][2], s2[nt][3])));
    m = fmaxf(m, __shfl_xor(m, 16));
    m = fmaxf(m, __shfl_xor(m, 32));
    float sum = 0.f;
#pragma unroll
    for (int nt = 0; nt < 13; nt++) {
#pragma unroll
        for (int r = 0; r < 4; r++) {
            float e = __expf(s2[nt][r] - m);
            s2[nt][r] = e; sum += e;
        }
    }
    sum += __shfl_xor(sum, 16);
    sum += __shfl_xor(sum, 32);
    float inv = 1.f / sum;

    // ---- stage V (+ zero pad cols 208..223)
#pragma unroll
    for (int j = 0; j < 7; j++) {
        int i = tid + j * 256;
        if (i < 1664) *(short8*)(sV + vd[j] * 232 + vc[j] * 8) = vv[j];
    }
    {
        int d = tid >> 2, c0 = 208 + (tid & 3) * 4;
        *(short4v*)(sV + d * 232 + c0) = (short4v){0,0,0,0};
    }
    __syncthreads();        // sV visible to all waves

    // ---- PV: per-ks wave-private P transpose through sP, K=224
    f32x4 o[4];
#pragma unroll
    for (int dt = 0; dt < 4; dt++) o[dt] = (f32x4){0.f,0.f,0.f,0.f};
#pragma unroll
    for (int ks = 0; ks < 7; ks++) {
        int ntA = 2 * ks;
        short4v w0, w1;
        w0.x = f2bf(s2[ntA][0] * inv); w0.y = f2bf(s2[ntA][1] * inv);
        w0.z = f2bf(s2[ntA][2] * inv); w0.w = f2bf(s2[ntA][3] * inv);
        if (ntA + 1 < 13) {
            w1.x = f2bf(s2[ntA+1][0] * inv); w1.y = f2bf(s2[ntA+1][1] * inv);
            w1.z = f2bf(s2[ntA+1][2] * inv); w1.w = f2bf(s2[ntA+1][3] * inv);
        } else w1 = (short4v){0,0,0,0};
        *(short4v*)(sP + prow * 40 + quad * 4) = w0;
        *(short4v*)(sP + prow * 40 + 16 + quad * 4) = w1;
        short8 aP = *(const short8*)(sP + prow * 40 + quad * 8);
#pragma unroll
        for (int dt = 0; dt < 4; dt++) {
            short8 bV = *(const short8*)(sV + (dt * 16 + l15) * 232 + ks * 32 + quad * 8);
            o[dt] = __builtin_amdgcn_mfma_f32_16x16x32_bf16(aP, bV, o[dt], 0, 0, 0);
        }
    }

    // ---- epilogue: v_local 9-tap from sV + BN + ReLU -> attT
#pragma unroll
    for (int r = 0; r < 4; r++) {
        int p = wave * 16 + quad * 4 + r;
        if (p >= 49) continue;
        int h2 = p / 7, w2 = p % 7;
#pragma unroll
        for (int dt = 0; dt < 4; dt++) {
            int d = dt * 16 + l15, c = h * 64 + d;
            float acc2 = vlb[c];
            const float* wc = vlw + c * 9;
            const short* vrow = sV + d * 232;
#pragma unroll
            for (int kh = 0; kh < 3; kh++) {
                int hin = 2 * h2 - 1 + kh;
                if (hin < 0 || hin >= 14) continue;
#pragma unroll
                for (int kk = 0; kk < 3; kk++) {
                    int win = 2 * w2 - 1 + kk;
                    if (win < 0 || win >= 14) continue;
                    acc2 += u2f((unsigned short)vrow[hin * 14 + win]) * wc[kh * 3 + kk];
                }
            }
            float vl = vlbs[c] * acc2 + vlbb[c];
            attT[((long)b * 64 + p) * 512 + h * 64 + d]
                = f2bf(fmaxf(o[dt][r] + vl, 0.f));
        }
    }
    for (int i = tid; i < 960; i += 256) {   // zero attT rows p 49..63
        int p = 49 + i / 64, d = i % 64;
        attT[((long)b * 64 + p) * 512 + h * 64 + d] = 0;
    }
}

// ---------------------------------------------------------------------------
// out = bn(conv1x1(relu(att))) via MFMA. XCD-grouped decode: 3 ocblks of one
// b share the attT slab via the same XCD's L2.
__global__ __launch_bounds__(256) void k_pconv_mfma(const short* __restrict__ attT,
        const short* __restrict__ pwb, const float* __restrict__ bias,
        const float* __restrict__ bns, const float* __restrict__ bnb,
        float* __restrict__ out) {
    __shared__ short sA[128 * 72];
    __shared__ short sB[64 * 72];
    int bid = blockIdx.x, tid = threadIdx.x;
    int tt = bid >> 3;
    int b = (bid & 7) * 32 + tt / 3;     // 768 = 8 XCD * 32 b * 3 ocblk
    int ocblk = tt % 3;
    int wave = tid >> 6, lane = tid & 63, quad = lane >> 4, l15 = lane & 15;
    int ocbase = ocblk * 128;

    f32x4 acc[2][4];
#pragma unroll
    for (int t = 0; t < 2; t++)
#pragma unroll
        for (int nt = 0; nt < 4; nt++) acc[t][nt] = (f32x4){0.f,0.f,0.f,0.f};

    for (int ct = 0; ct < 8; ct++) {
        for (int i = tid; i < 1024; i += 256) {
            int r = i >> 3, c8 = i & 7;
            *(short8*)(sA + r * 72 + c8 * 8)
                = *(const short8*)(pwb + (long)(ocbase + r) * 512 + ct * 64 + c8 * 8);
        }
        for (int i = tid; i < 512; i += 256) {
            int r = i >> 3, c8 = i & 7;
            *(short8*)(sB + r * 72 + c8 * 8)
                = *(const short8*)(attT + ((long)b * 64 + r) * 512 + ct * 64 + c8 * 8);
        }
        __syncthreads();
        short8 a00 = *(const short8*)(sA + (wave * 32 + l15) * 72 + quad * 8);
        short8 a01 = *(const short8*)(sA + (wave * 32 + l15) * 72 + 32 + quad * 8);
        short8 a10 = *(const short8*)(sA + (wave * 32 + 16 + l15) * 72 + quad * 8);
        short8 a11 = *(const short8*)(sA + (wave * 32 + 16 + l15) * 72 + 32 + quad * 8);
#pragma unroll
        for (int nt = 0; nt < 4; nt++) {
            short8 b0 = *(const short8*)(sB + (nt * 16 + l15) * 72 + quad * 8);
            short8 b1 = *(const short8*)(sB + (nt * 16 + l15) * 72 + 32 + quad * 8);
            acc[0][nt] = __builtin_amdgcn_mfma_f32_16x16x32_bf16(a00, b0, acc[0][nt], 0, 0, 0);
            acc[0][nt] = __builtin_amdgcn_mfma_f32_16x16x32_bf16(a01, b1, acc[0][nt], 0, 0, 0);
            acc[1][nt] = __builtin_amdgcn_mfma_f32_16x16x32_bf16(a10, b0, acc[1][nt], 0, 0, 0);
            acc[1][nt] = __builtin_amdgcn_mfma_f32_16x16x32_bf16(a11, b1, acc[1][nt], 0, 0, 0);
        }
        __syncthreads();
    }

#pragma unroll
    for (int t = 0; t < 2; t++) {
#pragma unroll
        for (int nt = 0; nt < 4; nt++) {
            int p = nt * 16 + l15;
            if (p >= 49) continue;
#pragma unroll
            for (int r = 0; r < 4; r++) {
                int oc = ocbase + wave * 32 + t * 16 + quad * 4 + r;
                out[((long)b * 384 + oc) * 49 + p]
                    = bns[oc] * (acc[t][nt][r] + bias[oc]) + bnb[oc];
            }
        }
    }
}

// ---------------------------------------------------------------------------
extern "C" void kernel_launch(void* const* d_in, const int* in_sizes, int n_in,
                              void* d_out, int out_size, void* d_ws, size_t ws_size,
                              hipStream_t stream) {
    const float* x    = (const float*)d_in[0];
    const float* qlw  = (const float*)d_in[1];
    const float* qlb  = (const float*)d_in[2];
    const float* qpw  = (const float*)d_in[3];
    const float* qpb  = (const float*)d_in[4];
    const float* qbs  = (const float*)d_in[5];
    const float* qbb  = (const float*)d_in[6];
    const float* kw   = (const float*)d_in[7];
    const float* kb   = (const float*)d_in[8];
    const float* kbs  = (const float*)d_in[9];
    const float* kbb  = (const float*)d_in[10];
    const float* vw   = (const float*)d_in[11];
    const float* vb   = (const float*)d_in[12];
    const float* vbs  = (const float*)d_in[13];
    const float* vbb  = (const float*)d_in[14];
    const float* vlw  = (const float*)d_in[15];
    const float* vlb  = (const float*)d_in[16];
    const float* vlbs = (const float*)d_in[17];
    const float* vlbb = (const float*)d_in[18];
    const float* btab = (const float*)d_in[19];
    const float* pw   = (const float*)d_in[20];
    const float* pb   = (const float*)d_in[21];
    const float* pbs  = (const float*)d_in[22];
    const float* pbb  = (const float*)d_in[23];
    float* out = (float*)d_out;

    char* W = (char*)d_ws;
    short* xT   = (short*)(W + 0);
    short* qinT = (short*)(W + 40894464);     // aliased by attT
    short* attT = (short*)(W + 40894464);
    short* q_t  = (short*)(W + 57671680);
    short* kbf  = (short*)(W + 60882944);
    short* vT   = (short*)(W + 88145920);
    short* wkv  = (short*)(W + 142671872);
    short* pwb  = (short*)(W + 143261696);    // end 143,654,912
    if (ws_size < 143654912) return;

    k_prep      <<< 3456, 256, 0, stream>>>(x, qlw, qlb, kw, vw, qpw, pw,
                                            xT, qinT, wkv, pwb);
    k_kv_mfma   <<< 1536, 256, 0, stream>>>(wkv, xT, qinT,
                                            kb, kbs, kbb, vb, vbs, vbb,
                                            qpb, qbs, qbb, kbf, vT, q_t);
    k_attn      <<< 2048, 256, 0, stream>>>(q_t, kbf, vT, btab,
                                            vlw, vlb, vlbs, vlbb, attT);
    k_pconv_mfma<<<  768, 256, 0, stream>>>(attT, pwb, pb, pbs, pbb, out);
}